// Round 7
// baseline (3325.939 us; speedup 1.0000x reference)
//
#include <hip/hip_runtime.h>
#include <hip/hip_bf16.h>
#include <math.h>

#define H 450
#define HP 464            // padded A row stride (bf16 elems; 928B rows, 16B-aligned)
#define KP 480            // padded K extent: 15 MFMA chunks of 32
#define LDSP 488          // scan LDS row stride (976B; 16B-aligned, conflict-free)
#define LAT 56
#define V 780
#define LW 24
#define NE 46
#define NF 23
#define SLOT (1024*HP)
#define SROWS 2048
#define QROWS (24*1024)
#define PROWS (47*1024)
#define PTGT  (23*1024)
#define QBLK 6144

typedef __hip_bfloat16 bf16;
typedef __attribute__((ext_vector_type(8))) short short8;
typedef __attribute__((ext_vector_type(4))) float f32x4;

#define MFMA16(a,b,c) __builtin_amdgcn_mfma_f32_16x16x32_bf16(a,b,c,0,0,0)

__device__ __forceinline__ float sigm(float x) { return 1.f / (1.f + expf(-x)); }
__device__ __forceinline__ float toF(bf16 x) { return __bfloat162float(x); }
__device__ __forceinline__ void stV(float* p, float v) { *p = v; }
__device__ __forceinline__ void stV(bf16* p, float v) { *p = __float2bfloat16(v); }
__device__ __forceinline__ short8 ld8(const bf16* p) { return *reinterpret_cast<const short8*>(p); }

// ---------------------------------------------------------------------------
__global__ __launch_bounds__(256)
void make_bt(const float* __restrict__ src, int K, int N, int ld,
             bf16* __restrict__ dst, int npad) {
    int idx = blockIdx.x * 256 + threadIdx.x;
    if (idx >= npad * KP) return;
    int n = idx / KP, k = idx - n * KP;
    float v = (n < N && k < K) ? src[(size_t)k * ld + n] : 0.f;
    dst[idx] = __float2bfloat16(v);
}

__global__ __launch_bounds__(256)
void zero_init(float* __restrict__ out, float* __restrict__ Sb, int n) {
    int i = blockIdx.x * 256 + threadIdx.x;
    if (i < 4) out[i] = 0.f;
    if (i < n) Sb[i] = 0.f;
}

// x_all[t*1024+n][h] = emb[wid[n][t]][h]  (bf16, stride HP)
__global__ __launch_bounds__(256)
void gather_x(const float* __restrict__ emb, const int* __restrict__ wid,
              bf16* __restrict__ x_all) {
    int e = blockIdx.x * 256 + threadIdx.x;
    if (e >= 24 * 1024 * 225) return;
    int row = e / 225, h2 = e - row * 225;
    int t = row >> 10, n = row & 1023;
    int v = wid[n * LW + t];
    float2 x = ((const float2*)(emb + (size_t)v * H))[h2];
    bf16* dst = x_all + (size_t)row * HP + 2 * h2;
    dst[0] = __float2bfloat16(x.x);
    dst[1] = __float2bfloat16(x.y);
}

// ---------------------------------------------------------------------------
// Row-panel MFMA GEMM: block = 64 rows x all cols (NFRAG frags of 16).
// A fetched once; B (<=0.5 MB) broadcast from L1/L2.
// Bt/C/bias pre-offset to the column block; ncols = valid cols.
// ---------------------------------------------------------------------------
template<int NFRAG, typename TC>
__global__ __launch_bounds__(256)
void gemm_rows(const bf16* __restrict__ A, int lda,
               const bf16* __restrict__ Bt, int ncols,
               TC* __restrict__ C, int ldc,
               const float* __restrict__ bias,
               const float* __restrict__ addrow, int addld, int relu) {
    int tid = threadIdx.x;
    int lane = tid & 63, wy = tid >> 6;
    int lrow = lane & 15, quad = lane >> 4;
    int row0 = blockIdx.x * 64;
    const bf16* Ap = A + (size_t)(row0 + wy * 16 + lrow) * lda + quad * 8;
    f32x4 acc[NFRAG];
#pragma unroll
    for (int f = 0; f < NFRAG; f++) acc[f] = (f32x4){0.f, 0.f, 0.f, 0.f};
    for (int k = 0; k < 15; k++) {
        short8 a = ld8(Ap + k * 32);
#pragma unroll
        for (int f = 0; f < NFRAG; f++) {
            short8 b = ld8(Bt + (size_t)(f * 16 + lrow) * KP + k * 32 + quad * 8);
            acc[f] = MFMA16(a, b, acc[f]);
        }
    }
    int r0 = row0 + wy * 16 + quad * 4;
#pragma unroll
    for (int f = 0; f < NFRAG; f++) {
        int c = f * 16 + lrow;
        if (c >= ncols) continue;
        float bi = bias ? bias[c] : 0.f;
#pragma unroll
        for (int e = 0; e < 4; e++) {
            int r = r0 + e;
            float v = acc[f][e] + bi;
            if (addrow) v += addrow[(size_t)(r & 1023) * addld + c];
            if (relu) v = fmaxf(v, 0.f);
            stV(&C[(size_t)r * ldc + c], v);
        }
    }
}

// Qtv/Ptv: out[n][c] = tv[n](56) @ Wlat(56x450) + bias[c]   grid(2,1024)
__global__ __launch_bounds__(256)
void tv_gemm(const float* __restrict__ tv, const float* __restrict__ Wlat,
             const float* __restrict__ bias, float* __restrict__ out) {
    int n = blockIdx.y;
    int c = blockIdx.x * 256 + threadIdx.x;
    __shared__ float tvs[LAT];
    if (threadIdx.x < LAT) tvs[threadIdx.x] = tv[n * LAT + threadIdx.x];
    __syncthreads();
    if (c < H) {
        float a = bias[c];
#pragma unroll 8
        for (int k = 0; k < LAT; k++) a += tvs[k] * Wlat[(size_t)k * H + c];
        out[(size_t)n * H + c] = a;
    }
}

// ---------------------------------------------------------------------------
// Fused scan step: block = 16 rows x all cols, 128 blocks, one launch/step.
// Phase1: z/h GEMMs (prev S from hs, prev RM) -> m_new -> Sb/hs/LDS.
// Phase2: r GEMM (A = m_new from LDS) -> RMb.  Waves col-split (f = w+4i).
// ---------------------------------------------------------------------------
__global__ __launch_bounds__(256)
void scan_step(bf16* __restrict__ hs, bf16* __restrict__ RMb,
               const bf16* __restrict__ WzbT, const bf16* __restrict__ WhbT,
               const bf16* __restrict__ UrT,
               const bf16* __restrict__ Xz, const bf16* __restrict__ Xh,
               const bf16* __restrict__ Xr, float* __restrict__ Sb, int u) {
    __shared__ bf16 mnl[16][LDSP];
    int tid = threadIdx.x;
    int lane = tid & 63, w = tid >> 6;
    int lrow = lane & 15, quad = lane >> 4;
    int row0 = blockIdx.x * 16;
    bool fwd = row0 < 1024;
    int rb = row0 & 1023;
    // zero LDS pad cols [H, LDSP)
    for (int i = tid; i < 16 * (LDSP - H); i += 256) {
        int rr = i / (LDSP - H), cc = H + (i - rr * (LDSP - H));
        mnl[rr][cc] = __float2bfloat16(0.f);
    }
    f32x4 az[8], ah[8];
#pragma unroll
    for (int i = 0; i < 8; i++) { az[i] = (f32x4){0.f,0.f,0.f,0.f}; ah[i] = (f32x4){0.f,0.f,0.f,0.f}; }
    if (u > 0) {
        const bf16* As = hs + (size_t)(fwd ? (u - 1) : (22 + u)) * SLOT
                         + (size_t)(rb + lrow) * HP + quad * 8;
        const bf16* Ar = RMb + (size_t)(row0 + lrow) * HP + quad * 8;
        for (int k = 0; k < 15; k++) {
            short8 sA = ld8(As + k * 32);
            short8 rA = ld8(Ar + k * 32);
#pragma unroll
            for (int i = 0; i < 8; i++) {
                int f = w + 4 * i;
                if (f >= 29) break;
                short8 zB = ld8(WzbT + (size_t)(f * 16 + lrow) * KP + k * 32 + quad * 8);
                short8 hB = ld8(WhbT + (size_t)(f * 16 + lrow) * KP + k * 32 + quad * 8);
                az[i] = MFMA16(sA, zB, az[i]);
                ah[i] = MFMA16(rA, hB, ah[i]);
            }
        }
    }
    int src = fwd ? u : 23 - u;
    bf16* hso = hs + (size_t)(fwd ? u : 23 + u) * SLOT;
#pragma unroll
    for (int i = 0; i < 8; i++) {
        int f = w + 4 * i;
        if (f >= 29) break;
        int c = f * 16 + lrow;
        if (c < H) {
#pragma unroll
            for (int e = 0; e < 4; e++) {
                int rl = quad * 4 + e;
                int r = row0 + rl;
                int n = r & 1023;
                float zp = az[i][e] + toF(Xz[((size_t)src * 1024 + n) * H + c]);
                float hp = ah[i][e] + toF(Xh[((size_t)src * 1024 + n) * H + c]);
                float s  = Sb[(size_t)r * H + c];
                float z  = sigm(zp);
                float mt = tanhf(hp);
                float mn = (1.f - z) * s + z * mt;
                Sb[(size_t)r * H + c] = mn;
                bf16 mb = __float2bfloat16(mn);
                hso[(size_t)n * HP + c] = mb;
                mnl[rl][c] = mb;
            }
        }
    }
    __syncthreads();
    if (u >= 22) return;
    f32x4 ar[8];
#pragma unroll
    for (int i = 0; i < 8; i++) ar[i] = (f32x4){0.f,0.f,0.f,0.f};
    for (int k = 0; k < 15; k++) {
        short8 a = *reinterpret_cast<const short8*>(&mnl[lrow][k * 32 + quad * 8]);
#pragma unroll
        for (int i = 0; i < 8; i++) {
            int f = w + 4 * i;
            if (f >= 29) break;
            short8 b = ld8(UrT + (size_t)(f * 16 + lrow) * KP + k * 32 + quad * 8);
            ar[i] = MFMA16(a, b, ar[i]);
        }
    }
    int dst = fwd ? (u + 1) : (22 - u);
#pragma unroll
    for (int i = 0; i < 8; i++) {
        int f = w + 4 * i;
        if (f >= 29) break;
        int c = f * 16 + lrow;
        if (c < H) {
#pragma unroll
            for (int e = 0; e < 4; e++) {
                int rl = quad * 4 + e;
                int r = row0 + rl;
                int n = r & 1023;
                float rp = ar[i][e] + toF(Xr[((size_t)dst * 1024 + n) * H + c]);
                float rr = sigm(rp);
                RMb[(size_t)r * HP + c] = __float2bfloat16(rr * toF(mnl[rl][c]));
            }
        }
    }
}

// hs[23+tl] += hs[21-tl] for tl in [0,22)
__global__ __launch_bounds__(256)
void hv_fixup(bf16* __restrict__ hs) {
    int idx = blockIdx.x * 256 + threadIdx.x;
    if (idx >= 22 * SLOT) return;
    int tl = idx / SLOT;
    int rem = idx - tl * SLOT;
    size_t a = (size_t)(23 + tl) * SLOT + rem;
    size_t b = (size_t)(21 - tl) * SLOT + rem;
    hs[a] = __float2bfloat16(toF(hs[a]) + toF(hs[b]));
}

// q_hidden root rows: relu(Qtv) -> qh rows 0..1023 (stride HP)
__global__ __launch_bounds__(256)
void q_root(const float* __restrict__ Qtv, bf16* __restrict__ qh) {
    int idx = blockIdx.x * 256 + threadIdx.x;
    if (idx >= 1024 * H) return;
    int n = idx / H, c = idx - n * H;
    qh[(size_t)n * HP + c] = __float2bfloat16(fmaxf(Qtv[idx], 0.f));
}

// q_reduce: wave-per-row online softmax + argmax -> per-block partials
__global__ __launch_bounds__(256)
void q_reduce(const float* __restrict__ ql, const int* __restrict__ wid,
              float* __restrict__ qred) {
    int wave = threadIdx.x >> 6, lane = threadIdx.x & 63;
    int r = blockIdx.x * 4 + wave;
    int t = r >> 10, n = r & 1023;
    int tgt = wid[n * LW + t];
    const float4* row4 = (const float4*)(ql + (size_t)r * V);
    float m = -3.4e38f, s = 0.f; int mi = 0x7fffffff;
#pragma unroll
    for (int k = 0; k < 4; k++) {
        int c4 = lane + 64 * k;
        if (c4 < 195) {
            float4 v4 = row4[c4];
            float vv[4] = {v4.x, v4.y, v4.z, v4.w};
#pragma unroll
            for (int e = 0; e < 4; e++) {
                float v = vv[e];
                if (v > m) { s = s * __expf(m - v) + 1.f; m = v; mi = c4 * 4 + e; }
                else s += __expf(v - m);
            }
        }
    }
#pragma unroll
    for (int off = 1; off < 64; off <<= 1) {
        float m2 = __shfl_xor(m, off);
        float s2 = __shfl_xor(s, off);
        int   i2 = __shfl_xor(mi, off);
        if (m2 > m || (m2 == m && i2 < mi)) {
            s = s2 + s * __expf(m - m2);
            m = m2; mi = i2;
        } else {
            s = s + s2 * __expf(m2 - m);
        }
    }
    __shared__ float lred[4][2];
    if (lane == 0) {
        float lse = m + logf(s);
        lred[wave][0] = lse - ql[(size_t)r * V + tgt];
        lred[wave][1] = (mi == tgt) ? 1.f : 0.f;
    }
    __syncthreads();
    if (threadIdx.x == 0) {
        qred[blockIdx.x * 2]     = lred[0][0] + lred[1][0] + lred[2][0] + lred[3][0];
        qred[blockIdx.x * 2 + 1] = lred[0][1] + lred[1][1] + lred[2][1] + lred[3][1];
    }
}

__global__ __launch_bounds__(256)
void q_final(const float* __restrict__ qred, float* __restrict__ out) {
    int tid = threadIdx.x;
    float L = 0.f, A = 0.f;
    for (int i = tid; i < QBLK; i += 256) { L += qred[2 * i]; A += qred[2 * i + 1]; }
    __shared__ float s1[256], s2[256];
    s1[tid] = L; s2[tid] = A;
    __syncthreads();
    for (int k = 128; k > 0; k >>= 1) {
        if (tid < k) { s1[tid] += s1[tid + k]; s2[tid] += s2[tid + k]; }
        __syncthreads();
    }
    if (tid == 0) {
        out[0] = s1[0] * (1.f / 1024.f);
        out[2] = s2[0] * (1.f / 24576.f);
    }
}

__global__ __launch_bounds__(256)
void p_init(float* __restrict__ pl, const float* __restrict__ Us_b) {
    int idx = blockIdx.x * 256 + threadIdx.x;
    if (idx < PROWS) pl[idx] = Us_b[0];
}

__global__ __launch_bounds__(256)
void p_root(const bf16* __restrict__ XUa, const float* __restrict__ Ptv,
            const float* __restrict__ Us, float* __restrict__ pl) {
    int n = blockIdx.x;
    int tid = threadIdx.x;
    const bf16* xa = XUa + (size_t)n * H;
    const float* pt = Ptv + (size_t)n * H;
    float s = 0.f;
    for (int c = tid; c < H; c += 256)
        s += fmaxf(toF(xa[c]) + pt[c], 0.f) * Us[c];
    __shared__ float red[256];
    red[tid] = s;
    __syncthreads();
    for (int k = 128; k > 0; k >>= 1) {
        if (tid < k) red[tid] += red[tid + k];
        __syncthreads();
    }
    if (tid == 0) atomicAdd(&pl[n], red[0]);
}

// p scan rows: row-panel GEMM hs @ Ub; relu(+XUa[dst]+Ptv) dot Us via shuffles
__global__ __launch_bounds__(256)
void p_gemm_rows(const bf16* __restrict__ hs, const bf16* __restrict__ UbT,
                 const bf16* __restrict__ XUa, const float* __restrict__ Ptv,
                 const float* __restrict__ Us, float* __restrict__ pl) {
    int tid = threadIdx.x;
    int lane = tid & 63, wy = tid >> 6;
    int lrow = lane & 15, quad = lane >> 4;
    int row0 = blockIdx.x * 64;
    const bf16* Ap = hs + (size_t)(row0 + wy * 16 + lrow) * HP + quad * 8;
    f32x4 acc[29];
#pragma unroll
    for (int f = 0; f < 29; f++) acc[f] = (f32x4){0.f, 0.f, 0.f, 0.f};
    for (int k = 0; k < 15; k++) {
        short8 a = ld8(Ap + k * 32);
#pragma unroll
        for (int f = 0; f < 29; f++) {
            short8 b = ld8(UbT + (size_t)(f * 16 + lrow) * KP + k * 32 + quad * 8);
            acc[f] = MFMA16(a, b, acc[f]);
        }
    }
    int r0 = row0 + wy * 16 + quad * 4;
    int t = row0 >> 10;                       // constant per block (64 | 1024)
    int dst = (t < 23) ? (t + 1) : (45 - t);
    float part[4] = {0.f, 0.f, 0.f, 0.f};
#pragma unroll
    for (int f = 0; f < 29; f++) {
        int c = f * 16 + lrow;
        if (c >= H) continue;
        float us = Us[c];
#pragma unroll
        for (int e = 0; e < 4; e++) {
            int n = (r0 + e) & 1023;
            float h = fmaxf(acc[f][e] + toF(XUa[((size_t)dst * 1024 + n) * H + c])
                            + Ptv[(size_t)n * H + c], 0.f);
            part[e] += h * us;
        }
    }
#pragma unroll
    for (int e = 0; e < 4; e++) {
#pragma unroll
        for (int off = 1; off < 16; off <<= 1)
            part[e] += __shfl_xor(part[e], off);
    }
    if (lrow == 0) {
#pragma unroll
        for (int e = 0; e < 4; e++)
            atomicAdd(&pl[1024 + r0 + e], part[e]);
    }
}

// BCE loss + accuracy over 48128 rows; target = (r < 23552)
__global__ __launch_bounds__(256)
void p_final(const float* __restrict__ pl, float* __restrict__ out) {
    int r = blockIdx.x * 256 + threadIdx.x;
    int tid = threadIdx.x;
    float loss = 0.f, acc = 0.f;
    if (r < PROWS) {
        float l = pl[r];
        int tgt = (r < PTGT) ? 1 : 0;
        float x = tgt ? -l : l;
        loss = fmaxf(x, 0.f) + log1pf(expf(-fabsf(x)));
        int pred = (l > 0.f) ? 1 : 0;
        acc = (pred == tgt) ? 1.f : 0.f;
    }
    __shared__ float s1[256], s2[256];
    s1[tid] = loss; s2[tid] = acc;
    __syncthreads();
    for (int k = 128; k > 0; k >>= 1) {
        if (tid < k) { s1[tid] += s1[tid + k]; s2[tid] += s2[tid + k]; }
        __syncthreads();
    }
    if (tid == 0) {
        atomicAdd(&out[1], s1[0] * (1.f / 1024.f));
        atomicAdd(&out[3], s2[0] * (1.f / 48128.f));
    }
}

// ---------------------------------------------------------------------------
extern "C" void kernel_launch(void* const* d_in, const int* in_sizes, int n_in,
                              void* d_out, int out_size, void* d_ws, size_t ws_size,
                              hipStream_t stream) {
    const int*   wid  = (const int*)  d_in[0];
    const float* tv   = (const float*)d_in[1];
    const float* emb  = (const float*)d_in[2];
    const float* W_w  = (const float*)d_in[3];
    const float* W_b  = (const float*)d_in[4];
    const float* U_w  = (const float*)d_in[5];
    const float* U_b  = (const float*)d_in[6];
    const float* Wo_w = (const float*)d_in[7];
    const float* Wo_b = (const float*)d_in[8];
    const float* Us_w = (const float*)d_in[9];
    const float* Us_b = (const float*)d_in[10];
    const float* Wz_w = (const float*)d_in[11];
    const float* Wz_b = (const float*)d_in[12];
    const float* Wr_w = (const float*)d_in[13];
    const float* Ur_w = (const float*)d_in[14];
    const float* Ur_b = (const float*)d_in[15];
    const float* Wh_w = (const float*)d_in[16];
    const float* Wh_b = (const float*)d_in[17];
    float* out = (float*)d_out;

    // ---- workspace layout (~147 MiB) ----
    char* base = (char*)d_ws;
    const size_t XBb = (size_t)QROWS * H * 2;
    bf16*  Xz   = (bf16*)(base);
    bf16*  Xh   = (bf16*)(base + XBb);
    bf16*  Xr   = (bf16*)(base + 2 * XBb);
    bf16*  XUa  = (bf16*)(base + 3 * XBb);
    bf16*  hs   = (bf16*)(base + 4 * XBb);               // 46 slots x 1024 x HP
    bf16*  x_all = hs;                                   // alias (dead before scan)
    char*  p1   = base + 4 * XBb + (size_t)NE * SLOT * 2;
    bf16*  RMb  = (bf16*)p1;                p1 += (size_t)SROWS * HP * 2;
    float* Sb   = (float*)p1;               p1 += (size_t)SROWS * H * 4;
    float* Qtv  = (float*)p1;               p1 += (size_t)1024 * H * 4;
    float* Ptv  = (float*)p1;               p1 += (size_t)1024 * H * 4;
    float* pl   = (float*)p1;               p1 += (size_t)PROWS * 4;
    float* qred = (float*)p1;               p1 += (size_t)QBLK * 2 * 4;
    bf16*  BT   = (bf16*)p1;
    const size_t BTS = (size_t)512 * KP;
    bf16 *WztT = BT,           *WhtT = BT + BTS,     *WrT = BT + 2*BTS,
         *UaT  = BT + 3*BTS,   *WzbT = BT + 4*BTS,   *WhbT = BT + 5*BTS,
         *UrT  = BT + 6*BTS,   *UbT  = BT + 7*BTS,   *WtopT = BT + 8*BTS,
         *WoT  = BT + 9*BTS;                             // 832*KP
    // q-path aliases (used after p path completes):
    bf16*  qh = (bf16*)base;                             // 24576 x HP bf16
    float* ql = (float*)(base + (size_t)QROWS * HP * 2); // 24576 x 780 f32

    // ---- init + weight prep ----
    zero_init<<<(SROWS * H + 255) / 256, 256, 0, stream>>>(out, Sb, SROWS * H);
    int btg = (512 * KP + 255) / 256;
    make_bt<<<btg, 256, 0, stream>>>(Wz_w,            H, H, H, WztT, 512);
    make_bt<<<btg, 256, 0, stream>>>(Wh_w,            H, H, H, WhtT, 512);
    make_bt<<<btg, 256, 0, stream>>>(Wr_w,            H, H, H, WrT,  512);
    make_bt<<<btg, 256, 0, stream>>>(U_w,             H, H, H, UaT,  512);
    make_bt<<<btg, 256, 0, stream>>>(Wz_w + 450*450,  H, H, H, WzbT, 512);
    make_bt<<<btg, 256, 0, stream>>>(Wh_w + 450*450,  H, H, H, WhbT, 512);
    make_bt<<<btg, 256, 0, stream>>>(Ur_w,            H, H, H, UrT,  512);
    make_bt<<<btg, 256, 0, stream>>>(U_w + 450*450,   H, H, H, UbT,  512);
    make_bt<<<btg, 256, 0, stream>>>(W_w,             H, H, H, WtopT, 512);
    make_bt<<<(832 * KP + 255) / 256, 256, 0, stream>>>(Wo_w, H, V, V, WoT, 832);

    // ---- embedding gather + per-node precomputes (row-panel GEMMs) ----
    gather_x<<<(24 * 1024 * 225 + 255) / 256, 256, 0, stream>>>(emb, wid, x_all);
    gemm_rows<29, bf16><<<QROWS / 64, 256, 0, stream>>>(x_all, HP, WztT, H, Xz,  H, Wz_b, (const float*)nullptr, H, 0);
    gemm_rows<29, bf16><<<QROWS / 64, 256, 0, stream>>>(x_all, HP, WhtT, H, Xh,  H, Wh_b, (const float*)nullptr, H, 0);
    gemm_rows<29, bf16><<<QROWS / 64, 256, 0, stream>>>(x_all, HP, WrT,  H, Xr,  H, Ur_b, (const float*)nullptr, H, 0);
    gemm_rows<29, bf16><<<QROWS / 64, 256, 0, stream>>>(x_all, HP, UaT,  H, XUa, H, (const float*)nullptr, (const float*)nullptr, H, 0);

    tv_gemm<<<dim3(2, 1024), 256, 0, stream>>>(tv, W_w + 450*450, W_b, Qtv);
    tv_gemm<<<dim3(2, 1024), 256, 0, stream>>>(tv, U_w + 900*450, U_b, Ptv);

    // ---- fused scan: 23 launches, 128 blocks each ----
    for (int u = 0; u < 23; u++)
        scan_step<<<SROWS / 16, 256, 0, stream>>>(hs, RMb, WzbT, WhbT, UrT,
                                                  Xz, Xh, Xr, Sb, u);
    hv_fixup<<<(22 * SLOT + 255) / 256, 256, 0, stream>>>(hs);

    // ---- p path (before q aliases X blocks / hs) ----
    p_init<<<(PROWS + 255) / 256, 256, 0, stream>>>(pl, Us_b);
    p_root<<<1024, 256, 0, stream>>>(XUa, Ptv, Us_w, pl);
    p_gemm_rows<<<(NE * 1024) / 64, 256, 0, stream>>>(hs, UbT, XUa, Ptv, Us_w, pl);
    p_final<<<PROWS / 256, 256, 0, stream>>>(pl, out);

    // ---- q path (qh over Xz/Xh; ql over Xr/XUa/hs-head) ----
    q_root<<<(1024 * H + 255) / 256, 256, 0, stream>>>(Qtv, qh);
    gemm_rows<29, bf16><<<(NF * 1024) / 64, 256, 0, stream>>>(hs, HP, WtopT, H,
                                                              qh + (size_t)1024 * HP, HP,
                                                              (const float*)nullptr, Qtv, H, 1);
    gemm_rows<25, float><<<QROWS / 64, 256, 0, stream>>>(qh, HP, WoT, 400, ql, V,
                                                         Wo_b, (const float*)nullptr, V, 0);
    gemm_rows<25, float><<<QROWS / 64, 256, 0, stream>>>(qh, HP, WoT + (size_t)400 * KP, 380,
                                                         ql + 400, V, Wo_b + 400,
                                                         (const float*)nullptr, V, 0);
    q_reduce<<<QBLK, 256, 0, stream>>>(ql, wid, qred);
    q_final<<<1, 256, 0, stream>>>(qred, out);

    (void)in_sizes; (void)n_in; (void)out_size; (void)ws_size;
}

// Round 8
// 1282.354 us; speedup vs baseline: 2.5936x; 2.5936x over previous
//
#include <hip/hip_runtime.h>
#include <hip/hip_bf16.h>
#include <math.h>

#define H 450
#define HP 464            // padded A row stride (bf16 elems; 16B-aligned rows)
#define KP 480            // padded K extent: 15 MFMA chunks of 32
#define LAT 56
#define V 780
#define LW 24
#define NE 46
#define NF 23
#define SLOT (1024*HP)
#define SROWS 2048
#define QROWS (24*1024)
#define PROWS (47*1024)
#define PTGT  (23*1024)
#define QBLK 6144

typedef __hip_bfloat16 bf16;
typedef __attribute__((ext_vector_type(8))) short short8;
typedef __attribute__((ext_vector_type(4))) float f32x4;

#define MFMA16(a,b,c) __builtin_amdgcn_mfma_f32_16x16x32_bf16(a,b,c,0,0,0)

__device__ __forceinline__ float sigm(float x) { return 1.f / (1.f + expf(-x)); }
__device__ __forceinline__ float toF(bf16 x) { return __bfloat162float(x); }
__device__ __forceinline__ void stV(float* p, float v) { *p = v; }
__device__ __forceinline__ void stV(bf16* p, float v) { *p = __float2bfloat16(v); }
__device__ __forceinline__ short8 ld8(const bf16* p) { return *reinterpret_cast<const short8*>(p); }

// XCD swizzle: all C col-tiles of a row-tile share b%8 -> same XCD L2.
// Requires (gridDim.x/C) % 8 == 0.
__device__ __forceinline__ void xcd_decode(int b, int C, int& row0, int& col0) {
    int rres = b & 7;
    int colt = (b >> 3) % C;
    int g    = b / (8 * C);
    row0 = (rres + 8 * g) * 64;
    col0 = colt * 64;
}

// ---------------------------------------------------------------------------
__global__ __launch_bounds__(256)
void make_bt(const float* __restrict__ src, int K, int N, int ld,
             bf16* __restrict__ dst, int npad) {
    int idx = blockIdx.x * 256 + threadIdx.x;
    if (idx >= npad * KP) return;
    int n = idx / KP, k = idx - n * KP;
    float v = (n < N && k < K) ? src[(size_t)k * ld + n] : 0.f;
    dst[idx] = __float2bfloat16(v);
}

__global__ __launch_bounds__(256)
void zero_init(float* __restrict__ out, float* __restrict__ Sb, int n) {
    int i = blockIdx.x * 256 + threadIdx.x;
    if (i < 4) out[i] = 0.f;
    if (i < n) Sb[i] = 0.f;
}

// x_all[t*1024+n][h] = emb[wid[n][t]][h]  (bf16, stride HP)
__global__ __launch_bounds__(256)
void gather_x(const float* __restrict__ emb, const int* __restrict__ wid,
              bf16* __restrict__ x_all) {
    int e = blockIdx.x * 256 + threadIdx.x;
    if (e >= 24 * 1024 * 225) return;
    int row = e / 225, h2 = e - row * 225;
    int t = row >> 10, n = row & 1023;
    int v = wid[n * LW + t];
    float2 x = ((const float2*)(emb + (size_t)v * H))[h2];
    bf16* dst = x_all + (size_t)row * HP + 2 * h2;
    dst[0] = __float2bfloat16(x.x);
    dst[1] = __float2bfloat16(x.y);
}

// ---------------------------------------------------------------------------
// Generic MFMA GEMM (64x64 tile, 2x2 frags/wave), XCD-swizzled 1-D grid.
// ---------------------------------------------------------------------------
template<typename TC>
__global__ __launch_bounds__(256)
void gemm_mfma(const bf16* __restrict__ A, int lda,
               const bf16* __restrict__ Bt, int N, int cblk,
               TC* __restrict__ C, int ldc,
               const float* __restrict__ bias,
               const float* __restrict__ addrow, int addld, int relu) {
    int tid = threadIdx.x;
    int lane = tid & 63, wave = tid >> 6;
    int wx = wave & 1, wy = wave >> 1;
    int lrow = lane & 15, quad = lane >> 4;
    int row0, col0;
    xcd_decode(blockIdx.x, cblk, row0, col0);
    const bf16* a0 = A + (size_t)(row0 + wy * 32 + lrow) * lda + quad * 8;
    const bf16* a1 = a0 + (size_t)16 * lda;
    const bf16* b0 = Bt + (size_t)(col0 + wx * 32 + lrow) * KP + quad * 8;
    const bf16* b1 = b0 + 16 * KP;
    f32x4 acc[2][2] = {};
    for (int k = 0; k < 15; k++) {
        short8 af0 = ld8(a0 + k * 32);
        short8 af1 = ld8(a1 + k * 32);
        short8 bf0 = ld8(b0 + k * 32);
        short8 bf1 = ld8(b1 + k * 32);
        acc[0][0] = MFMA16(af0, bf0, acc[0][0]);
        acc[0][1] = MFMA16(af0, bf1, acc[0][1]);
        acc[1][0] = MFMA16(af1, bf0, acc[1][0]);
        acc[1][1] = MFMA16(af1, bf1, acc[1][1]);
    }
#pragma unroll
    for (int i = 0; i < 2; i++)
#pragma unroll
        for (int e = 0; e < 4; e++) {
            int r = row0 + wy * 32 + i * 16 + quad * 4 + e;
#pragma unroll
            for (int j = 0; j < 2; j++) {
                int c = col0 + wx * 32 + j * 16 + lrow;
                if (c >= N) continue;
                float v = acc[i][j][e];
                if (bias) v += bias[c];
                if (addrow) v += addrow[(size_t)(r & 1023) * addld + c];
                if (relu) v = fmaxf(v, 0.f);
                stV(&C[(size_t)r * ldc + c], v);
            }
        }
}

// Qtv/Ptv: out[n][c] = tv[n](56) @ Wlat(56x450) + bias[c]   grid(2,1024)
__global__ __launch_bounds__(256)
void tv_gemm(const float* __restrict__ tv, const float* __restrict__ Wlat,
             const float* __restrict__ bias, float* __restrict__ out) {
    int n = blockIdx.y;
    int c = blockIdx.x * 256 + threadIdx.x;
    __shared__ float tvs[LAT];
    if (threadIdx.x < LAT) tvs[threadIdx.x] = tv[n * LAT + threadIdx.x];
    __syncthreads();
    if (c < H) {
        float a = bias[c];
#pragma unroll 8
        for (int k = 0; k < LAT; k++) a += tvs[k] * Wlat[(size_t)k * H + c];
        out[(size_t)n * H + c] = a;
    }
}

// ---------------------------------------------------------------------------
// Scan K1 (MFMA): z_pre = S@Wzb, h_pre = RM@Whb  (M=2048,N=450,K=450)
// grid = 256 linear, XCD-swizzled (C=8, R=32).
// ---------------------------------------------------------------------------
__global__ __launch_bounds__(256)
void scan_k1(const bf16* __restrict__ AsF, const bf16* __restrict__ AsB,
             const bf16* __restrict__ Arm,
             const bf16* __restrict__ BzT, const bf16* __restrict__ BhT,
             const bf16* __restrict__ Xz, const bf16* __restrict__ Xh,
             float* __restrict__ Sb, bf16* __restrict__ hsF, bf16* __restrict__ hsB,
             int u, int skip) {
    int tid = threadIdx.x;
    int lane = tid & 63, wave = tid >> 6;
    int wx = wave & 1, wy = wave >> 1;
    int lrow = lane & 15, quad = lane >> 4;
    int row0, col0;
    xcd_decode(blockIdx.x, 8, row0, col0);
    bool fwd = row0 < 1024;
    int rb = row0 & 1023;
    f32x4 az[2][2] = {}, ah[2][2] = {};
    if (!skip) {
        const bf16* As = (fwd ? AsF : AsB) + (size_t)(rb + wy * 32 + lrow) * HP + quad * 8;
        const bf16* Ar = Arm + (size_t)(row0 + wy * 32 + lrow) * HP + quad * 8;
        const bf16* bz0 = BzT + (size_t)(col0 + wx * 32 + lrow) * KP + quad * 8;
        const bf16* bh0 = BhT + (size_t)(col0 + wx * 32 + lrow) * KP + quad * 8;
        for (int k = 0; k < 15; k++) {
            short8 s0 = ld8(As + k * 32);
            short8 s1 = ld8(As + (size_t)16 * HP + k * 32);
            short8 r0 = ld8(Ar + k * 32);
            short8 r1 = ld8(Ar + (size_t)16 * HP + k * 32);
            short8 z0 = ld8(bz0 + k * 32);
            short8 z1 = ld8(bz0 + 16 * KP + k * 32);
            short8 h0 = ld8(bh0 + k * 32);
            short8 h1 = ld8(bh0 + 16 * KP + k * 32);
            az[0][0] = MFMA16(s0, z0, az[0][0]);
            az[0][1] = MFMA16(s0, z1, az[0][1]);
            az[1][0] = MFMA16(s1, z0, az[1][0]);
            az[1][1] = MFMA16(s1, z1, az[1][1]);
            ah[0][0] = MFMA16(r0, h0, ah[0][0]);
            ah[0][1] = MFMA16(r0, h1, ah[0][1]);
            ah[1][0] = MFMA16(r1, h0, ah[1][0]);
            ah[1][1] = MFMA16(r1, h1, ah[1][1]);
        }
    }
    int src = fwd ? u : 23 - u;
    bf16* hso = fwd ? hsF : hsB;
#pragma unroll
    for (int i = 0; i < 2; i++)
#pragma unroll
        for (int e = 0; e < 4; e++) {
            int r = row0 + wy * 32 + i * 16 + quad * 4 + e;
            int n = r & 1023;
#pragma unroll
            for (int j = 0; j < 2; j++) {
                int c = col0 + wx * 32 + j * 16 + lrow;
                if (c >= H) continue;
                float zp = az[i][j][e] + toF(Xz[((size_t)src * 1024 + n) * H + c]);
                float hp = ah[i][j][e] + toF(Xh[((size_t)src * 1024 + n) * H + c]);
                float s  = Sb[(size_t)r * H + c];
                float z  = sigm(zp);
                float mt = tanhf(hp);
                float mn = (1.f - z) * s + z * mt;
                Sb[(size_t)r * H + c] = mn;
                hso[(size_t)n * HP + c] = __float2bfloat16(mn);
            }
        }
}

// Scan K2 (MFMA): r_pre = Mnew@Ur + Xr[dst]; RMb = bf16(sig(r_pre)*Mnew)
__global__ __launch_bounds__(256)
void scan_k2(const bf16* __restrict__ AmF, const bf16* __restrict__ AmB,
             const bf16* __restrict__ UrT, const bf16* __restrict__ Xr,
             const float* __restrict__ Sb, bf16* __restrict__ RMb, int u) {
    int tid = threadIdx.x;
    int lane = tid & 63, wave = tid >> 6;
    int wx = wave & 1, wy = wave >> 1;
    int lrow = lane & 15, quad = lane >> 4;
    int row0, col0;
    xcd_decode(blockIdx.x, 8, row0, col0);
    bool fwd = row0 < 1024;
    int rb = row0 & 1023;
    const bf16* Am = (fwd ? AmF : AmB) + (size_t)(rb + wy * 32 + lrow) * HP + quad * 8;
    const bf16* b0 = UrT + (size_t)(col0 + wx * 32 + lrow) * KP + quad * 8;
    f32x4 acc[2][2] = {};
    for (int k = 0; k < 15; k++) {
        short8 a0 = ld8(Am + k * 32);
        short8 a1 = ld8(Am + (size_t)16 * HP + k * 32);
        short8 w0 = ld8(b0 + k * 32);
        short8 w1 = ld8(b0 + 16 * KP + k * 32);
        acc[0][0] = MFMA16(a0, w0, acc[0][0]);
        acc[0][1] = MFMA16(a0, w1, acc[0][1]);
        acc[1][0] = MFMA16(a1, w0, acc[1][0]);
        acc[1][1] = MFMA16(a1, w1, acc[1][1]);
    }
    int dst = fwd ? (u + 1) : (22 - u);
#pragma unroll
    for (int i = 0; i < 2; i++)
#pragma unroll
        for (int e = 0; e < 4; e++) {
            int r = row0 + wy * 32 + i * 16 + quad * 4 + e;
            int n = r & 1023;
#pragma unroll
            for (int j = 0; j < 2; j++) {
                int c = col0 + wx * 32 + j * 16 + lrow;
                if (c >= H) continue;
                float rp = acc[i][j][e] + toF(Xr[((size_t)dst * 1024 + n) * H + c]);
                float rr = sigm(rp);
                RMb[(size_t)r * HP + c] = __float2bfloat16(rr * Sb[(size_t)r * H + c]);
            }
        }
}

// hs[23+tl] += hs[21-tl] for tl in [0,22)
__global__ __launch_bounds__(256)
void hv_fixup(bf16* __restrict__ hs) {
    int idx = blockIdx.x * 256 + threadIdx.x;
    if (idx >= 22 * SLOT) return;
    int tl = idx / SLOT;
    int rem = idx - tl * SLOT;
    size_t a = (size_t)(23 + tl) * SLOT + rem;
    size_t b = (size_t)(21 - tl) * SLOT + rem;
    hs[a] = __float2bfloat16(toF(hs[a]) + toF(hs[b]));
}

// q_hidden root rows: relu(Qtv) -> qh rows 0..1023 (stride HP)
__global__ __launch_bounds__(256)
void q_root(const float* __restrict__ Qtv, bf16* __restrict__ qh) {
    int idx = blockIdx.x * 256 + threadIdx.x;
    if (idx >= 1024 * H) return;
    int n = idx / H, c = idx - n * H;
    qh[(size_t)n * HP + c] = __float2bfloat16(fmaxf(Qtv[idx], 0.f));
}

// q_reduce: wave-per-row online softmax + argmax -> per-block partials
__global__ __launch_bounds__(256)
void q_reduce(const float* __restrict__ ql, const int* __restrict__ wid,
              float* __restrict__ qred) {
    int wave = threadIdx.x >> 6, lane = threadIdx.x & 63;
    int r = blockIdx.x * 4 + wave;
    int t = r >> 10, n = r & 1023;
    int tgt = wid[n * LW + t];
    const float4* row4 = (const float4*)(ql + (size_t)r * V);
    float m = -3.4e38f, s = 0.f; int mi = 0x7fffffff;
#pragma unroll
    for (int k = 0; k < 4; k++) {
        int c4 = lane + 64 * k;
        if (c4 < 195) {
            float4 v4 = row4[c4];
            float vv[4] = {v4.x, v4.y, v4.z, v4.w};
#pragma unroll
            for (int e = 0; e < 4; e++) {
                float v = vv[e];
                if (v > m) { s = s * __expf(m - v) + 1.f; m = v; mi = c4 * 4 + e; }
                else s += __expf(v - m);
            }
        }
    }
#pragma unroll
    for (int off = 1; off < 64; off <<= 1) {
        float m2 = __shfl_xor(m, off);
        float s2 = __shfl_xor(s, off);
        int   i2 = __shfl_xor(mi, off);
        if (m2 > m || (m2 == m && i2 < mi)) {
            s = s2 + s * __expf(m - m2);
            m = m2; mi = i2;
        } else {
            s = s + s2 * __expf(m2 - m);
        }
    }
    __shared__ float lred[4][2];
    if (lane == 0) {
        float lse = m + logf(s);
        lred[wave][0] = lse - ql[(size_t)r * V + tgt];
        lred[wave][1] = (mi == tgt) ? 1.f : 0.f;
    }
    __syncthreads();
    if (threadIdx.x == 0) {
        qred[blockIdx.x * 2]     = lred[0][0] + lred[1][0] + lred[2][0] + lred[3][0];
        qred[blockIdx.x * 2 + 1] = lred[0][1] + lred[1][1] + lred[2][1] + lred[3][1];
    }
}

__global__ __launch_bounds__(256)
void q_final(const float* __restrict__ qred, float* __restrict__ out) {
    int tid = threadIdx.x;
    float L = 0.f, A = 0.f;
    for (int i = tid; i < QBLK; i += 256) { L += qred[2 * i]; A += qred[2 * i + 1]; }
    __shared__ float s1[256], s2[256];
    s1[tid] = L; s2[tid] = A;
    __syncthreads();
    for (int k = 128; k > 0; k >>= 1) {
        if (tid < k) { s1[tid] += s1[tid + k]; s2[tid] += s2[tid + k]; }
        __syncthreads();
    }
    if (tid == 0) {
        out[0] = s1[0] * (1.f / 1024.f);
        out[2] = s2[0] * (1.f / 24576.f);
    }
}

__global__ __launch_bounds__(256)
void p_init(float* __restrict__ pl, const float* __restrict__ Us_b) {
    int idx = blockIdx.x * 256 + threadIdx.x;
    if (idx < PROWS) pl[idx] = Us_b[0];
}

__global__ __launch_bounds__(256)
void p_root(const bf16* __restrict__ XUa, const float* __restrict__ Ptv,
            const float* __restrict__ Us, float* __restrict__ pl) {
    int n = blockIdx.x;
    int tid = threadIdx.x;
    const bf16* xa = XUa + (size_t)n * H;
    const float* pt = Ptv + (size_t)n * H;
    float s = 0.f;
    for (int c = tid; c < H; c += 256)
        s += fmaxf(toF(xa[c]) + pt[c], 0.f) * Us[c];
    __shared__ float red[256];
    red[tid] = s;
    __syncthreads();
    for (int k = 128; k > 0; k >>= 1) {
        if (tid < k) red[tid] += red[tid + k];
        __syncthreads();
    }
    if (tid == 0) atomicAdd(&pl[n], red[0]);
}

// p scan rows (MFMA, XCD-swizzled): hs @ Ub; relu(+XUa[dst]+Ptv) dot Us -> pl
__global__ __launch_bounds__(256)
void p_gemm(const bf16* __restrict__ hs, const bf16* __restrict__ UbT,
            const bf16* __restrict__ XUa, const float* __restrict__ Ptv,
            const float* __restrict__ Us, float* __restrict__ pl) {
    int tid = threadIdx.x;
    int lane = tid & 63, wave = tid >> 6;
    int wx = wave & 1, wy = wave >> 1;
    int lrow = lane & 15, quad = lane >> 4;
    int row0, col0;
    xcd_decode(blockIdx.x, 8, row0, col0);
    const bf16* a0 = hs + (size_t)(row0 + wy * 32 + lrow) * HP + quad * 8;
    const bf16* b0 = UbT + (size_t)(col0 + wx * 32 + lrow) * KP + quad * 8;
    f32x4 acc[2][2] = {};
    for (int k = 0; k < 15; k++) {
        short8 af0 = ld8(a0 + k * 32);
        short8 af1 = ld8(a0 + (size_t)16 * HP + k * 32);
        short8 bf0 = ld8(b0 + k * 32);
        short8 bf1 = ld8(b0 + 16 * KP + k * 32);
        acc[0][0] = MFMA16(af0, bf0, acc[0][0]);
        acc[0][1] = MFMA16(af0, bf1, acc[0][1]);
        acc[1][0] = MFMA16(af1, bf0, acc[1][0]);
        acc[1][1] = MFMA16(af1, bf1, acc[1][1]);
    }
    __shared__ float red[64][32];
#pragma unroll
    for (int i = 0; i < 2; i++)
#pragma unroll
        for (int e = 0; e < 4; e++) {
            int rl = wy * 32 + i * 16 + quad * 4 + e;
            int r = row0 + rl;
            int t = r >> 10, n = r & 1023;
            int dst = (t < 23) ? (t + 1) : (45 - t);
            float partial = 0.f;
#pragma unroll
            for (int j = 0; j < 2; j++) {
                int c = col0 + wx * 32 + j * 16 + lrow;
                if (c < H) {
                    float h = fmaxf(acc[i][j][e] + toF(XUa[((size_t)dst * 1024 + n) * H + c])
                                    + Ptv[(size_t)n * H + c], 0.f);
                    partial += h * Us[c];
                }
            }
            red[rl][wx * 16 + lrow] = partial;
        }
    __syncthreads();
    if (tid < 64) {
        float s = 0.f;
#pragma unroll
        for (int k = 0; k < 32; k++) s += red[tid][k];
        atomicAdd(&pl[1024 + row0 + tid], s);
    }
}

// BCE loss + accuracy over 48128 rows; target = (r < 23552)
__global__ __launch_bounds__(256)
void p_final(const float* __restrict__ pl, float* __restrict__ out) {
    int r = blockIdx.x * 256 + threadIdx.x;
    int tid = threadIdx.x;
    float loss = 0.f, acc = 0.f;
    if (r < PROWS) {
        float l = pl[r];
        int tgt = (r < PTGT) ? 1 : 0;
        float x = tgt ? -l : l;
        loss = fmaxf(x, 0.f) + log1pf(expf(-fabsf(x)));
        int pred = (l > 0.f) ? 1 : 0;
        acc = (pred == tgt) ? 1.f : 0.f;
    }
    __shared__ float s1[256], s2[256];
    s1[tid] = loss; s2[tid] = acc;
    __syncthreads();
    for (int k = 128; k > 0; k >>= 1) {
        if (tid < k) { s1[tid] += s1[tid + k]; s2[tid] += s2[tid + k]; }
        __syncthreads();
    }
    if (tid == 0) {
        atomicAdd(&out[1], s1[0] * (1.f / 1024.f));
        atomicAdd(&out[3], s2[0] * (1.f / 48128.f));
    }
}

// ---------------------------------------------------------------------------
extern "C" void kernel_launch(void* const* d_in, const int* in_sizes, int n_in,
                              void* d_out, int out_size, void* d_ws, size_t ws_size,
                              hipStream_t stream) {
    const int*   wid  = (const int*)  d_in[0];
    const float* tv   = (const float*)d_in[1];
    const float* emb  = (const float*)d_in[2];
    const float* W_w  = (const float*)d_in[3];
    const float* W_b  = (const float*)d_in[4];
    const float* U_w  = (const float*)d_in[5];
    const float* U_b  = (const float*)d_in[6];
    const float* Wo_w = (const float*)d_in[7];
    const float* Wo_b = (const float*)d_in[8];
    const float* Us_w = (const float*)d_in[9];
    const float* Us_b = (const float*)d_in[10];
    const float* Wz_w = (const float*)d_in[11];
    const float* Wz_b = (const float*)d_in[12];
    const float* Wr_w = (const float*)d_in[13];
    const float* Ur_w = (const float*)d_in[14];
    const float* Ur_b = (const float*)d_in[15];
    const float* Wh_w = (const float*)d_in[16];
    const float* Wh_b = (const float*)d_in[17];
    float* out = (float*)d_out;

    // ---- workspace layout (~147 MiB) ----
    char* base = (char*)d_ws;
    const size_t XBb = (size_t)QROWS * H * 2;
    bf16*  Xz   = (bf16*)(base);
    bf16*  Xh   = (bf16*)(base + XBb);
    bf16*  Xr   = (bf16*)(base + 2 * XBb);
    bf16*  XUa  = (bf16*)(base + 3 * XBb);
    bf16*  hs   = (bf16*)(base + 4 * XBb);               // 46 slots x 1024 x HP
    bf16*  x_all = hs;                                   // alias (dead before scan)
    char*  p1   = base + 4 * XBb + (size_t)NE * SLOT * 2;
    bf16*  RMb  = (bf16*)p1;                p1 += (size_t)SROWS * HP * 2;
    float* Sb   = (float*)p1;               p1 += (size_t)SROWS * H * 4;
    float* Qtv  = (float*)p1;               p1 += (size_t)1024 * H * 4;
    float* Ptv  = (float*)p1;               p1 += (size_t)1024 * H * 4;
    float* pl   = (float*)p1;               p1 += (size_t)PROWS * 4;
    float* qred = (float*)p1;               p1 += (size_t)QBLK * 2 * 4;
    bf16*  BT   = (bf16*)p1;
    const size_t BTS = (size_t)512 * KP;
    bf16 *WztT = BT,           *WhtT = BT + BTS,     *WrT = BT + 2*BTS,
         *UaT  = BT + 3*BTS,   *WzbT = BT + 4*BTS,   *WhbT = BT + 5*BTS,
         *UrT  = BT + 6*BTS,   *UbT  = BT + 7*BTS,   *WtopT = BT + 8*BTS,
         *WoT  = BT + 9*BTS;                             // 832*KP
    // q-path aliases (used after p path completes):
    bf16*  qh = (bf16*)base;                             // 24576 x HP bf16
    float* ql = (float*)(base + (size_t)QROWS * HP * 2); // 24576 x 780 f32

    // ---- init + weight prep ----
    zero_init<<<(SROWS * H + 255) / 256, 256, 0, stream>>>(out, Sb, SROWS * H);
    int btg = (512 * KP + 255) / 256;
    make_bt<<<btg, 256, 0, stream>>>(Wz_w,            H, H, H, WztT, 512);
    make_bt<<<btg, 256, 0, stream>>>(Wh_w,            H, H, H, WhtT, 512);
    make_bt<<<btg, 256, 0, stream>>>(Wr_w,            H, H, H, WrT,  512);
    make_bt<<<btg, 256, 0, stream>>>(U_w,             H, H, H, UaT,  512);
    make_bt<<<btg, 256, 0, stream>>>(Wz_w + 450*450,  H, H, H, WzbT, 512);
    make_bt<<<btg, 256, 0, stream>>>(Wh_w + 450*450,  H, H, H, WhbT, 512);
    make_bt<<<btg, 256, 0, stream>>>(Ur_w,            H, H, H, UrT,  512);
    make_bt<<<btg, 256, 0, stream>>>(U_w + 450*450,   H, H, H, UbT,  512);
    make_bt<<<btg, 256, 0, stream>>>(W_w,             H, H, H, WtopT, 512);
    make_bt<<<(832 * KP + 255) / 256, 256, 0, stream>>>(Wo_w, H, V, V, WoT, 832);

    // ---- embedding gather + per-node precomputes (XCD-swizzled GEMMs) ----
    gather_x<<<(24 * 1024 * 225 + 255) / 256, 256, 0, stream>>>(emb, wid, x_all);
    int gPre = 8 * (QROWS / 64);                         // 3072 blocks
    gemm_mfma<bf16><<<gPre, 256, 0, stream>>>(x_all, HP, WztT, H, 8, Xz,  H, Wz_b, (const float*)nullptr, H, 0);
    gemm_mfma<bf16><<<gPre, 256, 0, stream>>>(x_all, HP, WhtT, H, 8, Xh,  H, Wh_b, (const float*)nullptr, H, 0);
    gemm_mfma<bf16><<<gPre, 256, 0, stream>>>(x_all, HP, WrT,  H, 8, Xr,  H, Ur_b, (const float*)nullptr, H, 0);
    gemm_mfma<bf16><<<gPre, 256, 0, stream>>>(x_all, HP, UaT,  H, 8, XUa, H, (const float*)nullptr, (const float*)nullptr, H, 0);

    tv_gemm<<<dim3(2, 1024), 256, 0, stream>>>(tv, W_w + 450*450, W_b, Qtv);
    tv_gemm<<<dim3(2, 1024), 256, 0, stream>>>(tv, U_w + 900*450, U_b, Ptv);

    // ---- sequential scan: 23 steps, fwd+bwd chains batched (M=2048) ----
    for (int u = 0; u < 23; u++) {
        const bf16* AsF = hs + (size_t)(u - 1) * SLOT;        // valid only u>0
        const bf16* AsB = hs + (size_t)(22 + u) * SLOT;
        scan_k1<<<256, 256, 0, stream>>>(AsF, AsB, RMb, WzbT, WhbT, Xz, Xh,
                                         Sb, hs + (size_t)u * SLOT,
                                         hs + (size_t)(23 + u) * SLOT, u, u == 0 ? 1 : 0);
        if (u < 22)
            scan_k2<<<256, 256, 0, stream>>>(hs + (size_t)u * SLOT, hs + (size_t)(23 + u) * SLOT,
                                             UrT, Xr, Sb, RMb, u);
    }
    hv_fixup<<<(22 * SLOT + 255) / 256, 256, 0, stream>>>(hs);

    // ---- p path (before q aliases X blocks / hs) ----
    p_init<<<(PROWS + 255) / 256, 256, 0, stream>>>(pl, Us_b);
    p_root<<<1024, 256, 0, stream>>>(XUa, Ptv, Us_w, pl);
    p_gemm<<<8 * (NE * 1024 / 64), 256, 0, stream>>>(hs, UbT, XUa, Ptv, Us_w, pl);
    p_final<<<PROWS / 256, 256, 0, stream>>>(pl, out);

    // ---- q path (qh over Xz/Xh; ql over Xr/XUa/hs-head) ----
    q_root<<<(1024 * H + 255) / 256, 256, 0, stream>>>(Qtv, qh);
    gemm_mfma<bf16><<<8 * (NF * 1024 / 64), 256, 0, stream>>>(hs, HP, WtopT, H, 8,
                                                              qh + (size_t)1024 * HP, HP,
                                                              (const float*)nullptr, Qtv, H, 1);
    gemm_mfma<float><<<13 * (QROWS / 64), 256, 0, stream>>>(qh, HP, WoT, V, 13, ql, V,
                                                            Wo_b, (const float*)nullptr, H, 0);
    q_reduce<<<QBLK, 256, 0, stream>>>(ql, wid, qred);
    q_final<<<1, 256, 0, stream>>>(qred, out);

    (void)in_sizes; (void)n_in; (void)out_size; (void)ws_size;
}

// Round 9
// 1197.494 us; speedup vs baseline: 2.7774x; 1.0709x over previous
//
#include <hip/hip_runtime.h>
#include <hip/hip_bf16.h>
#include <math.h>

#define H 450
#define HP 464            // padded A row stride (bf16 elems; 16B-aligned rows)
#define KP 480            // padded K extent: 15 MFMA chunks of 32
#define LAT 56
#define V 780
#define LW 24
#define NE 46
#define NF 23
#define SLOT (1024*HP)
#define SROWS 2048
#define QROWS (24*1024)
#define PROWS (47*1024)
#define PTGT  (23*1024)
#define QBLK 6144

typedef __hip_bfloat16 bf16;
typedef __attribute__((ext_vector_type(8))) short short8;
typedef __attribute__((ext_vector_type(4))) float f32x4;

#define MFMA16(a,b,c) __builtin_amdgcn_mfma_f32_16x16x32_bf16(a,b,c,0,0,0)

__device__ __forceinline__ float sigm(float x) { return 1.f / (1.f + expf(-x)); }
__device__ __forceinline__ float toF(bf16 x) { return __bfloat162float(x); }
__device__ __forceinline__ void stV(float* p, float v) { *p = v; }
__device__ __forceinline__ void stV(bf16* p, float v) { *p = __float2bfloat16(v); }
__device__ __forceinline__ short8 ld8(const bf16* p) { return *reinterpret_cast<const short8*>(p); }

// async global->LDS, 16B/lane; LDS dest is wave-uniform base + lane*16
__device__ __forceinline__ void gl_lds(const bf16* g, bf16* l) {
    __builtin_amdgcn_global_load_lds(
        (const __attribute__((address_space(1))) void*)g,
        (__attribute__((address_space(3))) void*)l, 16, 0, 0);
}

// XCD swizzle (64-tiles): all C col-tiles of a row-tile share b%8 -> same XCD L2
__device__ __forceinline__ void xcd_decode(int b, int C, int& row0, int& col0) {
    int rres = b & 7;
    int colt = (b >> 3) % C;
    int g    = b / (8 * C);
    row0 = (rres + 8 * g) * 64;
    col0 = colt * 64;
}
// 128-tile variant
__device__ __forceinline__ void xcd_decode128(int b, int C, int& row0, int& col0) {
    int rres = b & 7;
    int colt = (b >> 3) % C;
    int g    = b / (8 * C);
    row0 = (rres + 8 * g) * 128;
    col0 = colt * 128;
}

// ---------------------------------------------------------------------------
__global__ __launch_bounds__(256)
void make_bt(const float* __restrict__ src, int K, int N, int ld,
             bf16* __restrict__ dst, int npad) {
    int idx = blockIdx.x * 256 + threadIdx.x;
    if (idx >= npad * KP) return;
    int n = idx / KP, k = idx - n * KP;
    float v = (n < N && k < K) ? src[(size_t)k * ld + n] : 0.f;
    dst[idx] = __float2bfloat16(v);
}

__global__ __launch_bounds__(256)
void zero_init(float* __restrict__ out, float* __restrict__ Sb, int n) {
    int i = blockIdx.x * 256 + threadIdx.x;
    if (i < 4) out[i] = 0.f;
    if (i < n) Sb[i] = 0.f;
}

// x_all[t*1024+n][h] = emb[wid[n][t]][h]  (bf16, stride HP)
__global__ __launch_bounds__(256)
void gather_x(const float* __restrict__ emb, const int* __restrict__ wid,
              bf16* __restrict__ x_all) {
    int e = blockIdx.x * 256 + threadIdx.x;
    if (e >= 24 * 1024 * 225) return;
    int row = e / 225, h2 = e - row * 225;
    int t = row >> 10, n = row & 1023;
    int v = wid[n * LW + t];
    float2 x = ((const float2*)(emb + (size_t)v * H))[h2];
    bf16* dst = x_all + (size_t)row * HP + 2 * h2;
    dst[0] = __float2bfloat16(x.x);
    dst[1] = __float2bfloat16(x.y);
}

// ---------------------------------------------------------------------------
// m97-style LDS-staged GEMM: 128x128 tile, BK=32, global_load_lds staging,
// 4 waves (2x2), each wave 64x64 = 4x4 frags. XCD-swizzled 1-D grid.
// ---------------------------------------------------------------------------
template<typename TC>
__global__ __launch_bounds__(256)
void gemm128(const bf16* __restrict__ A, int lda,
             const bf16* __restrict__ Bt, int N, int cblk,
             TC* __restrict__ C, int ldc,
             const float* __restrict__ bias,
             const float* __restrict__ addrow, int addld, int relu) {
    __shared__ bf16 As[128 * 32];
    __shared__ bf16 Bs[128 * 32];
    int tid = threadIdx.x;
    int lane = tid & 63, wave = tid >> 6;
    int wx = wave & 1, wy = wave >> 1;
    int lrow = lane & 15, quad = lane >> 4;
    int row0, col0;
    xcd_decode128(blockIdx.x, cblk, row0, col0);
    f32x4 acc[4][4] = {};
    for (int k0i = 0; k0i < 15; k0i++) {
        int k0 = k0i * 32;
#pragma unroll
        for (int r = 0; r < 2; r++) {
            int t = r * 256 + tid;
            int row = t >> 2, ko = (t & 3) * 8;
            gl_lds(A  + (size_t)(row0 + row) * lda + k0 + ko, As + t * 8);
            gl_lds(Bt + (size_t)(col0 + row) * KP  + k0 + ko, Bs + t * 8);
        }
        __syncthreads();
        short8 a[4], b[4];
#pragma unroll
        for (int f = 0; f < 4; f++)
            a[f] = ld8(As + (wy * 64 + f * 16 + lrow) * 32 + quad * 8);
#pragma unroll
        for (int f = 0; f < 4; f++)
            b[f] = ld8(Bs + (wx * 64 + f * 16 + lrow) * 32 + quad * 8);
#pragma unroll
        for (int fi = 0; fi < 4; fi++)
#pragma unroll
            for (int fj = 0; fj < 4; fj++)
                acc[fi][fj] = MFMA16(a[fi], b[fj], acc[fi][fj]);
        __syncthreads();
    }
#pragma unroll
    for (int fi = 0; fi < 4; fi++)
#pragma unroll
        for (int e = 0; e < 4; e++) {
            int r = row0 + wy * 64 + fi * 16 + quad * 4 + e;
#pragma unroll
            for (int fj = 0; fj < 4; fj++) {
                int c = col0 + wx * 64 + fj * 16 + lrow;
                if (c >= N) continue;
                float v = acc[fi][fj][e];
                if (bias) v += bias[c];
                if (addrow) v += addrow[(size_t)(r & 1023) * addld + c];
                if (relu) v = fmaxf(v, 0.f);
                stV(&C[(size_t)r * ldc + c], v);
            }
        }
}

// p GEMM, staged: hs @ Ub; epilogue relu(+XUa[dst]+Ptv) dot Us -> atomic pl
__global__ __launch_bounds__(256)
void p_gemm128(const bf16* __restrict__ hs, const bf16* __restrict__ UbT,
               const bf16* __restrict__ XUa, const float* __restrict__ Ptv,
               const float* __restrict__ Us, float* __restrict__ pl) {
    __shared__ bf16 As[128 * 32];
    __shared__ bf16 Bs[128 * 32];
    int tid = threadIdx.x;
    int lane = tid & 63, wave = tid >> 6;
    int wx = wave & 1, wy = wave >> 1;
    int lrow = lane & 15, quad = lane >> 4;
    int row0, col0;
    xcd_decode128(blockIdx.x, 4, row0, col0);
    f32x4 acc[4][4] = {};
    for (int k0i = 0; k0i < 15; k0i++) {
        int k0 = k0i * 32;
#pragma unroll
        for (int r = 0; r < 2; r++) {
            int t = r * 256 + tid;
            int row = t >> 2, ko = (t & 3) * 8;
            gl_lds(hs  + (size_t)(row0 + row) * HP + k0 + ko, As + t * 8);
            gl_lds(UbT + (size_t)(col0 + row) * KP + k0 + ko, Bs + t * 8);
        }
        __syncthreads();
        short8 a[4], b[4];
#pragma unroll
        for (int f = 0; f < 4; f++)
            a[f] = ld8(As + (wy * 64 + f * 16 + lrow) * 32 + quad * 8);
#pragma unroll
        for (int f = 0; f < 4; f++)
            b[f] = ld8(Bs + (wx * 64 + f * 16 + lrow) * 32 + quad * 8);
#pragma unroll
        for (int fi = 0; fi < 4; fi++)
#pragma unroll
            for (int fj = 0; fj < 4; fj++)
                acc[fi][fj] = MFMA16(a[fi], b[fj], acc[fi][fj]);
        __syncthreads();
    }
    int t0 = row0 >> 10;                // may span two t within a 128-row tile? no: row0 mult of 128, 1024%128==0 -> t constant per 128 rows? 128*8=1024: rows row0..row0+127 same t iff row0%1024 <= 896: true since row0 mult of 128 and tile fits in one t-block
#pragma unroll
    for (int fi = 0; fi < 4; fi++)
#pragma unroll
        for (int e = 0; e < 4; e++) {
            int r = row0 + wy * 64 + fi * 16 + quad * 4 + e;
            int t = r >> 10, n = r & 1023;
            int dst = (t < 23) ? (t + 1) : (45 - t);
            float part = 0.f;
#pragma unroll
            for (int fj = 0; fj < 4; fj++) {
                int c = col0 + wx * 64 + fj * 16 + lrow;
                if (c < H) {
                    float h = fmaxf(acc[fi][fj][e] + toF(XUa[((size_t)dst * 1024 + n) * H + c])
                                    + Ptv[(size_t)n * H + c], 0.f);
                    part += h * Us[c];
                }
            }
#pragma unroll
            for (int off = 1; off < 16; off <<= 1)
                part += __shfl_xor(part, off);
            if (lrow == 0) atomicAdd(&pl[1024 + r], part);
        }
    (void)t0;
}

// Qtv/Ptv: out[n][c] = tv[n](56) @ Wlat(56x450) + bias[c]   grid(2,1024)
__global__ __launch_bounds__(256)
void tv_gemm(const float* __restrict__ tv, const float* __restrict__ Wlat,
             const float* __restrict__ bias, float* __restrict__ out) {
    int n = blockIdx.y;
    int c = blockIdx.x * 256 + threadIdx.x;
    __shared__ float tvs[LAT];
    if (threadIdx.x < LAT) tvs[threadIdx.x] = tv[n * LAT + threadIdx.x];
    __syncthreads();
    if (c < H) {
        float a = bias[c];
#pragma unroll 8
        for (int k = 0; k < LAT; k++) a += tvs[k] * Wlat[(size_t)k * H + c];
        out[(size_t)n * H + c] = a;
    }
}

// ---------------------------------------------------------------------------
// Scan K1 (MFMA, 64x64, XCD-swizzled): z_pre = S@Wzb, h_pre = RM@Whb
// ---------------------------------------------------------------------------
__global__ __launch_bounds__(256)
void scan_k1(const bf16* __restrict__ AsF, const bf16* __restrict__ AsB,
             const bf16* __restrict__ Arm,
             const bf16* __restrict__ BzT, const bf16* __restrict__ BhT,
             const bf16* __restrict__ Xz, const bf16* __restrict__ Xh,
             float* __restrict__ Sb, bf16* __restrict__ hsF, bf16* __restrict__ hsB,
             int u, int skip) {
    int tid = threadIdx.x;
    int lane = tid & 63, wave = tid >> 6;
    int wx = wave & 1, wy = wave >> 1;
    int lrow = lane & 15, quad = lane >> 4;
    int row0, col0;
    xcd_decode(blockIdx.x, 8, row0, col0);
    bool fwd = row0 < 1024;
    int rb = row0 & 1023;
    f32x4 az[2][2] = {}, ah[2][2] = {};
    if (!skip) {
        const bf16* As = (fwd ? AsF : AsB) + (size_t)(rb + wy * 32 + lrow) * HP + quad * 8;
        const bf16* Ar = Arm + (size_t)(row0 + wy * 32 + lrow) * HP + quad * 8;
        const bf16* bz0 = BzT + (size_t)(col0 + wx * 32 + lrow) * KP + quad * 8;
        const bf16* bh0 = BhT + (size_t)(col0 + wx * 32 + lrow) * KP + quad * 8;
        for (int k = 0; k < 15; k++) {
            short8 s0 = ld8(As + k * 32);
            short8 s1 = ld8(As + (size_t)16 * HP + k * 32);
            short8 r0 = ld8(Ar + k * 32);
            short8 r1 = ld8(Ar + (size_t)16 * HP + k * 32);
            short8 z0 = ld8(bz0 + k * 32);
            short8 z1 = ld8(bz0 + 16 * KP + k * 32);
            short8 h0 = ld8(bh0 + k * 32);
            short8 h1 = ld8(bh0 + 16 * KP + k * 32);
            az[0][0] = MFMA16(s0, z0, az[0][0]);
            az[0][1] = MFMA16(s0, z1, az[0][1]);
            az[1][0] = MFMA16(s1, z0, az[1][0]);
            az[1][1] = MFMA16(s1, z1, az[1][1]);
            ah[0][0] = MFMA16(r0, h0, ah[0][0]);
            ah[0][1] = MFMA16(r0, h1, ah[0][1]);
            ah[1][0] = MFMA16(r1, h0, ah[1][0]);
            ah[1][1] = MFMA16(r1, h1, ah[1][1]);
        }
    }
    int src = fwd ? u : 23 - u;
    bf16* hso = fwd ? hsF : hsB;
#pragma unroll
    for (int i = 0; i < 2; i++)
#pragma unroll
        for (int e = 0; e < 4; e++) {
            int r = row0 + wy * 32 + i * 16 + quad * 4 + e;
            int n = r & 1023;
#pragma unroll
            for (int j = 0; j < 2; j++) {
                int c = col0 + wx * 32 + j * 16 + lrow;
                if (c >= H) continue;
                float zp = az[i][j][e] + toF(Xz[((size_t)src * 1024 + n) * H + c]);
                float hp = ah[i][j][e] + toF(Xh[((size_t)src * 1024 + n) * H + c]);
                float s  = Sb[(size_t)r * H + c];
                float z  = sigm(zp);
                float mt = tanhf(hp);
                float mn = (1.f - z) * s + z * mt;
                Sb[(size_t)r * H + c] = mn;
                hso[(size_t)n * HP + c] = __float2bfloat16(mn);
            }
        }
}

// Scan K2 (MFMA): r_pre = Mnew@Ur + Xr[dst]; RMb = bf16(sig(r_pre)*Mnew)
__global__ __launch_bounds__(256)
void scan_k2(const bf16* __restrict__ AmF, const bf16* __restrict__ AmB,
             const bf16* __restrict__ UrT, const bf16* __restrict__ Xr,
             const float* __restrict__ Sb, bf16* __restrict__ RMb, int u) {
    int tid = threadIdx.x;
    int lane = tid & 63, wave = tid >> 6;
    int wx = wave & 1, wy = wave >> 1;
    int lrow = lane & 15, quad = lane >> 4;
    int row0, col0;
    xcd_decode(blockIdx.x, 8, row0, col0);
    bool fwd = row0 < 1024;
    int rb = row0 & 1023;
    const bf16* Am = (fwd ? AmF : AmB) + (size_t)(rb + wy * 32 + lrow) * HP + quad * 8;
    const bf16* b0 = UrT + (size_t)(col0 + wx * 32 + lrow) * KP + quad * 8;
    f32x4 acc[2][2] = {};
    for (int k = 0; k < 15; k++) {
        short8 a0 = ld8(Am + k * 32);
        short8 a1 = ld8(Am + (size_t)16 * HP + k * 32);
        short8 w0 = ld8(b0 + k * 32);
        short8 w1 = ld8(b0 + 16 * KP + k * 32);
        acc[0][0] = MFMA16(a0, w0, acc[0][0]);
        acc[0][1] = MFMA16(a0, w1, acc[0][1]);
        acc[1][0] = MFMA16(a1, w0, acc[1][0]);
        acc[1][1] = MFMA16(a1, w1, acc[1][1]);
    }
    int dst = fwd ? (u + 1) : (22 - u);
#pragma unroll
    for (int i = 0; i < 2; i++)
#pragma unroll
        for (int e = 0; e < 4; e++) {
            int r = row0 + wy * 32 + i * 16 + quad * 4 + e;
            int n = r & 1023;
#pragma unroll
            for (int j = 0; j < 2; j++) {
                int c = col0 + wx * 32 + j * 16 + lrow;
                if (c >= H) continue;
                float rp = acc[i][j][e] + toF(Xr[((size_t)dst * 1024 + n) * H + c]);
                float rr = sigm(rp);
                RMb[(size_t)r * HP + c] = __float2bfloat16(rr * Sb[(size_t)r * H + c]);
            }
        }
}

// hs[23+tl] += hs[21-tl] for tl in [0,22)
__global__ __launch_bounds__(256)
void hv_fixup(bf16* __restrict__ hs) {
    int idx = blockIdx.x * 256 + threadIdx.x;
    if (idx >= 22 * SLOT) return;
    int tl = idx / SLOT;
    int rem = idx - tl * SLOT;
    size_t a = (size_t)(23 + tl) * SLOT + rem;
    size_t b = (size_t)(21 - tl) * SLOT + rem;
    hs[a] = __float2bfloat16(toF(hs[a]) + toF(hs[b]));
}

// q_hidden root rows: relu(Qtv) -> qh rows 0..1023 (stride HP)
__global__ __launch_bounds__(256)
void q_root(const float* __restrict__ Qtv, bf16* __restrict__ qh) {
    int idx = blockIdx.x * 256 + threadIdx.x;
    if (idx >= 1024 * H) return;
    int n = idx / H, c = idx - n * H;
    qh[(size_t)n * HP + c] = __float2bfloat16(fmaxf(Qtv[idx], 0.f));
}

// q_reduce: wave-per-row online softmax + argmax -> per-block partials
__global__ __launch_bounds__(256)
void q_reduce(const float* __restrict__ ql, const int* __restrict__ wid,
              float* __restrict__ qred) {
    int wave = threadIdx.x >> 6, lane = threadIdx.x & 63;
    int r = blockIdx.x * 4 + wave;
    int t = r >> 10, n = r & 1023;
    int tgt = wid[n * LW + t];
    const float4* row4 = (const float4*)(ql + (size_t)r * V);
    float m = -3.4e38f, s = 0.f; int mi = 0x7fffffff;
#pragma unroll
    for (int k = 0; k < 4; k++) {
        int c4 = lane + 64 * k;
        if (c4 < 195) {
            float4 v4 = row4[c4];
            float vv[4] = {v4.x, v4.y, v4.z, v4.w};
#pragma unroll
            for (int e = 0; e < 4; e++) {
                float v = vv[e];
                if (v > m) { s = s * __expf(m - v) + 1.f; m = v; mi = c4 * 4 + e; }
                else s += __expf(v - m);
            }
        }
    }
#pragma unroll
    for (int off = 1; off < 64; off <<= 1) {
        float m2 = __shfl_xor(m, off);
        float s2 = __shfl_xor(s, off);
        int   i2 = __shfl_xor(mi, off);
        if (m2 > m || (m2 == m && i2 < mi)) {
            s = s2 + s * __expf(m - m2);
            m = m2; mi = i2;
        } else {
            s = s + s2 * __expf(m2 - m);
        }
    }
    __shared__ float lred[4][2];
    if (lane == 0) {
        float lse = m + logf(s);
        lred[wave][0] = lse - ql[(size_t)r * V + tgt];
        lred[wave][1] = (mi == tgt) ? 1.f : 0.f;
    }
    __syncthreads();
    if (threadIdx.x == 0) {
        qred[blockIdx.x * 2]     = lred[0][0] + lred[1][0] + lred[2][0] + lred[3][0];
        qred[blockIdx.x * 2 + 1] = lred[0][1] + lred[1][1] + lred[2][1] + lred[3][1];
    }
}

__global__ __launch_bounds__(256)
void q_final(const float* __restrict__ qred, float* __restrict__ out) {
    int tid = threadIdx.x;
    float L = 0.f, A = 0.f;
    for (int i = tid; i < QBLK; i += 256) { L += qred[2 * i]; A += qred[2 * i + 1]; }
    __shared__ float s1[256], s2[256];
    s1[tid] = L; s2[tid] = A;
    __syncthreads();
    for (int k = 128; k > 0; k >>= 1) {
        if (tid < k) { s1[tid] += s1[tid + k]; s2[tid] += s2[tid + k]; }
        __syncthreads();
    }
    if (tid == 0) {
        out[0] = s1[0] * (1.f / 1024.f);
        out[2] = s2[0] * (1.f / 24576.f);
    }
}

__global__ __launch_bounds__(256)
void p_init(float* __restrict__ pl, const float* __restrict__ Us_b) {
    int idx = blockIdx.x * 256 + threadIdx.x;
    if (idx < PROWS) pl[idx] = Us_b[0];
}

__global__ __launch_bounds__(256)
void p_root(const bf16* __restrict__ XUa, const float* __restrict__ Ptv,
            const float* __restrict__ Us, float* __restrict__ pl) {
    int n = blockIdx.x;
    int tid = threadIdx.x;
    const bf16* xa = XUa + (size_t)n * H;
    const float* pt = Ptv + (size_t)n * H;
    float s = 0.f;
    for (int c = tid; c < H; c += 256)
        s += fmaxf(toF(xa[c]) + pt[c], 0.f) * Us[c];
    __shared__ float red[256];
    red[tid] = s;
    __syncthreads();
    for (int k = 128; k > 0; k >>= 1) {
        if (tid < k) red[tid] += red[tid + k];
        __syncthreads();
    }
    if (tid == 0) atomicAdd(&pl[n], red[0]);
}

// BCE loss + accuracy over 48128 rows; target = (r < 23552)
__global__ __launch_bounds__(256)
void p_final(const float* __restrict__ pl, float* __restrict__ out) {
    int r = blockIdx.x * 256 + threadIdx.x;
    int tid = threadIdx.x;
    float loss = 0.f, acc = 0.f;
    if (r < PROWS) {
        float l = pl[r];
        int tgt = (r < PTGT) ? 1 : 0;
        float x = tgt ? -l : l;
        loss = fmaxf(x, 0.f) + log1pf(expf(-fabsf(x)));
        int pred = (l > 0.f) ? 1 : 0;
        acc = (pred == tgt) ? 1.f : 0.f;
    }
    __shared__ float s1[256], s2[256];
    s1[tid] = loss; s2[tid] = acc;
    __syncthreads();
    for (int k = 128; k > 0; k >>= 1) {
        if (tid < k) { s1[tid] += s1[tid + k]; s2[tid] += s2[tid + k]; }
        __syncthreads();
    }
    if (tid == 0) {
        atomicAdd(&out[1], s1[0] * (1.f / 1024.f));
        atomicAdd(&out[3], s2[0] * (1.f / 48128.f));
    }
}

// ---------------------------------------------------------------------------
extern "C" void kernel_launch(void* const* d_in, const int* in_sizes, int n_in,
                              void* d_out, int out_size, void* d_ws, size_t ws_size,
                              hipStream_t stream) {
    const int*   wid  = (const int*)  d_in[0];
    const float* tv   = (const float*)d_in[1];
    const float* emb  = (const float*)d_in[2];
    const float* W_w  = (const float*)d_in[3];
    const float* W_b  = (const float*)d_in[4];
    const float* U_w  = (const float*)d_in[5];
    const float* U_b  = (const float*)d_in[6];
    const float* Wo_w = (const float*)d_in[7];
    const float* Wo_b = (const float*)d_in[8];
    const float* Us_w = (const float*)d_in[9];
    const float* Us_b = (const float*)d_in[10];
    const float* Wz_w = (const float*)d_in[11];
    const float* Wz_b = (const float*)d_in[12];
    const float* Wr_w = (const float*)d_in[13];
    const float* Ur_w = (const float*)d_in[14];
    const float* Ur_b = (const float*)d_in[15];
    const float* Wh_w = (const float*)d_in[16];
    const float* Wh_b = (const float*)d_in[17];
    float* out = (float*)d_out;

    // ---- workspace layout (~147 MiB) ----
    char* base = (char*)d_ws;
    const size_t XBb = (size_t)QROWS * H * 2;
    bf16*  Xz   = (bf16*)(base);
    bf16*  Xh   = (bf16*)(base + XBb);
    bf16*  Xr   = (bf16*)(base + 2 * XBb);
    bf16*  XUa  = (bf16*)(base + 3 * XBb);
    bf16*  hs   = (bf16*)(base + 4 * XBb);               // 46 slots x 1024 x HP
    bf16*  x_all = hs;                                   // alias (dead before scan)
    char*  p1   = base + 4 * XBb + (size_t)NE * SLOT * 2;
    bf16*  RMb  = (bf16*)p1;                p1 += (size_t)SROWS * HP * 2;
    float* Sb   = (float*)p1;               p1 += (size_t)SROWS * H * 4;
    float* Qtv  = (float*)p1;               p1 += (size_t)1024 * H * 4;
    float* Ptv  = (float*)p1;               p1 += (size_t)1024 * H * 4;
    float* pl   = (float*)p1;               p1 += (size_t)PROWS * 4;
    float* qred = (float*)p1;               p1 += (size_t)QBLK * 2 * 4;
    bf16*  BT   = (bf16*)p1;
    const size_t BTS = (size_t)512 * KP;
    bf16 *WztT = BT,           *WhtT = BT + BTS,     *WrT = BT + 2*BTS,
         *UaT  = BT + 3*BTS,   *WzbT = BT + 4*BTS,   *WhbT = BT + 5*BTS,
         *UrT  = BT + 6*BTS,   *UbT  = BT + 7*BTS,   *WtopT = BT + 8*BTS,
         *WoT  = BT + 9*BTS;                             // 896*KP
    // q-path aliases (used after p path completes):
    bf16*  qh = (bf16*)base;                             // 24576 x HP bf16
    float* ql = (float*)(base + (size_t)QROWS * HP * 2); // 24576 x 780 f32

    // ---- init + weight prep ----
    zero_init<<<(SROWS * H + 255) / 256, 256, 0, stream>>>(out, Sb, SROWS * H);
    int btg = (512 * KP + 255) / 256;
    make_bt<<<btg, 256, 0, stream>>>(Wz_w,            H, H, H, WztT, 512);
    make_bt<<<btg, 256, 0, stream>>>(Wh_w,            H, H, H, WhtT, 512);
    make_bt<<<btg, 256, 0, stream>>>(Wr_w,            H, H, H, WrT,  512);
    make_bt<<<btg, 256, 0, stream>>>(U_w,             H, H, H, UaT,  512);
    make_bt<<<btg, 256, 0, stream>>>(Wz_w + 450*450,  H, H, H, WzbT, 512);
    make_bt<<<btg, 256, 0, stream>>>(Wh_w + 450*450,  H, H, H, WhbT, 512);
    make_bt<<<btg, 256, 0, stream>>>(Ur_w,            H, H, H, UrT,  512);
    make_bt<<<btg, 256, 0, stream>>>(U_w + 450*450,   H, H, H, UbT,  512);
    make_bt<<<btg, 256, 0, stream>>>(W_w,             H, H, H, WtopT, 512);
    make_bt<<<(896 * KP + 255) / 256, 256, 0, stream>>>(Wo_w, H, V, V, WoT, 896);

    // ---- embedding gather + per-node precomputes (staged 128-tile GEMMs) ----
    gather_x<<<(24 * 1024 * 225 + 255) / 256, 256, 0, stream>>>(emb, wid, x_all);
    int gPre = (QROWS / 128) * 4;                        // 768 blocks, C=4
    gemm128<bf16><<<gPre, 256, 0, stream>>>(x_all, HP, WztT, H, 4, Xz,  H, Wz_b, (const float*)nullptr, H, 0);
    gemm128<bf16><<<gPre, 256, 0, stream>>>(x_all, HP, WhtT, H, 4, Xh,  H, Wh_b, (const float*)nullptr, H, 0);
    gemm128<bf16><<<gPre, 256, 0, stream>>>(x_all, HP, WrT,  H, 4, Xr,  H, Ur_b, (const float*)nullptr, H, 0);
    gemm128<bf16><<<gPre, 256, 0, stream>>>(x_all, HP, UaT,  H, 4, XUa, H, (const float*)nullptr, (const float*)nullptr, H, 0);

    tv_gemm<<<dim3(2, 1024), 256, 0, stream>>>(tv, W_w + 450*450, W_b, Qtv);
    tv_gemm<<<dim3(2, 1024), 256, 0, stream>>>(tv, U_w + 900*450, U_b, Ptv);

    // ---- sequential scan: 23 steps, fwd+bwd chains batched (M=2048) ----
    for (int u = 0; u < 23; u++) {
        const bf16* AsF = hs + (size_t)(u - 1) * SLOT;        // valid only u>0
        const bf16* AsB = hs + (size_t)(22 + u) * SLOT;
        scan_k1<<<256, 256, 0, stream>>>(AsF, AsB, RMb, WzbT, WhbT, Xz, Xh,
                                         Sb, hs + (size_t)u * SLOT,
                                         hs + (size_t)(23 + u) * SLOT, u, u == 0 ? 1 : 0);
        if (u < 22)
            scan_k2<<<256, 256, 0, stream>>>(hs + (size_t)u * SLOT, hs + (size_t)(23 + u) * SLOT,
                                             UrT, Xr, Sb, RMb, u);
    }
    hv_fixup<<<(22 * SLOT + 255) / 256, 256, 0, stream>>>(hs);

    // ---- p path (before q aliases X blocks / hs) ----
    p_init<<<(PROWS + 255) / 256, 256, 0, stream>>>(pl, Us_b);
    p_root<<<1024, 256, 0, stream>>>(XUa, Ptv, Us_w, pl);
    p_gemm128<<<(PROWS - 1024) / 128 * 4, 256, 0, stream>>>(hs, UbT, XUa, Ptv, Us_w, pl);
    p_final<<<PROWS / 256, 256, 0, stream>>>(pl, out);

    // ---- q path (qh over Xz/Xh; ql over Xr/XUa/hs-head) ----
    q_root<<<(1024 * H + 255) / 256, 256, 0, stream>>>(Qtv, qh);
    gemm128<bf16><<<(NF * 1024 / 128) * 4, 256, 0, stream>>>(hs, HP, WtopT, H, 4,
                                                             qh + (size_t)1024 * HP, HP,
                                                             (const float*)nullptr, Qtv, H, 1);
    gemm128<float><<<(QROWS / 128) * 7, 256, 0, stream>>>(qh, HP, WoT, V, 7, ql, V,
                                                          Wo_b, (const float*)nullptr, H, 0);
    q_reduce<<<QBLK, 256, 0, stream>>>(ql, wid, qred);
    q_final<<<1, 256, 0, stream>>>(qred, out);

    (void)in_sizes; (void)n_in; (void)out_size; (void)ws_size;
}

// Round 10
// 1103.649 us; speedup vs baseline: 3.0136x; 1.0850x over previous
//
#include <hip/hip_runtime.h>
#include <hip/hip_bf16.h>
#include <math.h>

#define H 450
#define HP 464            // padded A row stride (bf16 elems; 16B-aligned rows)
#define KP 480            // padded K extent: 15 MFMA chunks of 32
#define LAT 56
#define V 780
#define LW 24
#define NE 46
#define NF 23
#define SLOT (1024*HP)
#define SROWS 2048
#define QROWS (24*1024)
#define PROWS (47*1024)
#define PTGT  (23*1024)
#define QBLK 6144
#define XBSZ ((size_t)QROWS * H)      // one X block, elems

typedef __hip_bfloat16 bf16;
typedef __attribute__((ext_vector_type(8))) short short8;
typedef __attribute__((ext_vector_type(4))) float f32x4;

#define MFMA16(a,b,c) __builtin_amdgcn_mfma_f32_16x16x32_bf16(a,b,c,0,0,0)

__device__ __forceinline__ float sigm(float x) { return 1.f / (1.f + expf(-x)); }
__device__ __forceinline__ float toF(bf16 x) { return __bfloat162float(x); }
__device__ __forceinline__ void stV(float* p, float v) { *p = v; }
__device__ __forceinline__ void stV(bf16* p, float v) { *p = __float2bfloat16(v); }
__device__ __forceinline__ short8 ld8(const bf16* p) { return *reinterpret_cast<const short8*>(p); }

// async global->LDS, 16B/lane; LDS dest is wave-uniform base + lane*16
__device__ __forceinline__ void gl_lds(const bf16* g, bf16* l) {
    __builtin_amdgcn_global_load_lds(
        (const __attribute__((address_space(1))) void*)g,
        (__attribute__((address_space(3))) void*)l, 16, 0, 0);
}

// XCD swizzle (64-tiles)
__device__ __forceinline__ void xcd_decode(int b, int C, int& row0, int& col0) {
    int rres = b & 7;
    int colt = (b >> 3) % C;
    int g    = b / (8 * C);
    row0 = (rres + 8 * g) * 64;
    col0 = colt * 64;
}
// 128-tile variant
__device__ __forceinline__ void xcd_decode128(int b, int C, int& row0, int& col0) {
    int rres = b & 7;
    int colt = (b >> 3) % C;
    int g    = b / (8 * C);
    row0 = (rres + 8 * g) * 128;
    col0 = colt * 128;
}

// ---------------------------------------------------------------------------
__global__ __launch_bounds__(256)
void make_bt(const float* __restrict__ src, int K, int N, int ld,
             bf16* __restrict__ dst, int npad) {
    int idx = blockIdx.x * 256 + threadIdx.x;
    if (idx >= npad * KP) return;
    int n = idx / KP, k = idx - n * KP;
    float v = (n < N && k < K) ? src[(size_t)k * ld + n] : 0.f;
    dst[idx] = __float2bfloat16(v);
}

// combined bias for fused pre-GEMM: [Wz_b | Wh_b | Ur_b | 0]
__global__ __launch_bounds__(256)
void pack_bias(const float* __restrict__ zb, const float* __restrict__ hb,
               const float* __restrict__ rb, float* __restrict__ bias4) {
    int i = blockIdx.x * 256 + threadIdx.x;
    if (i >= 1856) return;
    float v = 0.f;
    if (i < 450)       v = zb[i];
    else if (i < 900)  v = hb[i - 450];
    else if (i < 1350) v = rb[i - 900];
    bias4[i] = v;
}

__global__ __launch_bounds__(256)
void zero_init(float* __restrict__ out, float* __restrict__ Sb, int n) {
    int i = blockIdx.x * 256 + threadIdx.x;
    if (i < 4) out[i] = 0.f;
    if (i < n) Sb[i] = 0.f;
}

// x_all[t*1024+n][h] = emb[wid[n][t]][h]  (bf16, stride HP)
__global__ __launch_bounds__(256)
void gather_x(const float* __restrict__ emb, const int* __restrict__ wid,
              bf16* __restrict__ x_all) {
    int e = blockIdx.x * 256 + threadIdx.x;
    if (e >= 24 * 1024 * 225) return;
    int row = e / 225, h2 = e - row * 225;
    int t = row >> 10, n = row & 1023;
    int v = wid[n * LW + t];
    float2 x = ((const float2*)(emb + (size_t)v * H))[h2];
    bf16* dst = x_all + (size_t)row * HP + 2 * h2;
    dst[0] = __float2bfloat16(x.x);
    dst[1] = __float2bfloat16(x.y);
}

// ---------------------------------------------------------------------------
// LDS-staged GEMM: 128x128 tile, BK=32, global_load_lds + rotate swizzle
// (chunk (row,c) at row*4 + ((c+(row>>1))&3) -> 2-way-free ds_read banks).
// ---------------------------------------------------------------------------
template<typename TC>
__global__ __launch_bounds__(256)
void gemm128(const bf16* __restrict__ A, int lda,
             const bf16* __restrict__ Bt, int N, int cblk,
             TC* __restrict__ C, int ldc,
             const float* __restrict__ bias,
             const float* __restrict__ addrow, int addld, int relu) {
    __shared__ bf16 As[128 * 32];
    __shared__ bf16 Bs[128 * 32];
    int tid = threadIdx.x;
    int lane = tid & 63, wave = tid >> 6;
    int wx = wave & 1, wy = wave >> 1;
    int lrow = lane & 15, quad = lane >> 4;
    int perm = ((quad + (lrow >> 1)) & 3) * 8;
    int row0, col0;
    xcd_decode128(blockIdx.x, cblk, row0, col0);
    f32x4 acc[4][4] = {};
    for (int k0i = 0; k0i < 15; k0i++) {
        int k0 = k0i * 32;
#pragma unroll
        for (int r = 0; r < 2; r++) {
            int tt = r * 256 + tid;
            int row = tt >> 2, cl = tt & 3;
            int cg = (cl - (row >> 1)) & 3;
            gl_lds(A  + (size_t)(row0 + row) * lda + k0 + cg * 8, As + tt * 8);
            gl_lds(Bt + (size_t)(col0 + row) * KP  + k0 + cg * 8, Bs + tt * 8);
        }
        __syncthreads();
        short8 a[4], b[4];
#pragma unroll
        for (int f = 0; f < 4; f++)
            a[f] = ld8(As + (wy * 64 + f * 16 + lrow) * 32 + perm);
#pragma unroll
        for (int f = 0; f < 4; f++)
            b[f] = ld8(Bs + (wx * 64 + f * 16 + lrow) * 32 + perm);
#pragma unroll
        for (int fi = 0; fi < 4; fi++)
#pragma unroll
            for (int fj = 0; fj < 4; fj++)
                acc[fi][fj] = MFMA16(a[fi], b[fj], acc[fi][fj]);
        __syncthreads();
    }
#pragma unroll
    for (int fi = 0; fi < 4; fi++)
#pragma unroll
        for (int e = 0; e < 4; e++) {
            int r = row0 + wy * 64 + fi * 16 + quad * 4 + e;
#pragma unroll
            for (int fj = 0; fj < 4; fj++) {
                int c = col0 + wx * 64 + fj * 16 + lrow;
                if (c >= N) continue;
                float v = acc[fi][fj][e];
                if (bias) v += bias[c];
                if (addrow) v += addrow[(size_t)(r & 1023) * addld + c];
                if (relu) v = fmaxf(v, 0.f);
                stV(&C[(size_t)r * ldc + c], v);
            }
        }
}

// Fused pre-GEMM: X @ [Wz|Wh|Wr|Ua] (N=1800), demux epilogue into 4 X blocks
__global__ __launch_bounds__(256)
void gemm128_pre(const bf16* __restrict__ A,
                 const bf16* __restrict__ Bt,
                 bf16* __restrict__ X0,          // Xz; blocks stride XBSZ
                 const float* __restrict__ bias4) {
    __shared__ bf16 As[128 * 32];
    __shared__ bf16 Bs[128 * 32];
    int tid = threadIdx.x;
    int lane = tid & 63, wave = tid >> 6;
    int wx = wave & 1, wy = wave >> 1;
    int lrow = lane & 15, quad = lane >> 4;
    int perm = ((quad + (lrow >> 1)) & 3) * 8;
    int row0, col0;
    xcd_decode128(blockIdx.x, 15, row0, col0);
    f32x4 acc[4][4] = {};
    for (int k0i = 0; k0i < 15; k0i++) {
        int k0 = k0i * 32;
#pragma unroll
        for (int r = 0; r < 2; r++) {
            int tt = r * 256 + tid;
            int row = tt >> 2, cl = tt & 3;
            int cg = (cl - (row >> 1)) & 3;
            gl_lds(A  + (size_t)(row0 + row) * HP + k0 + cg * 8, As + tt * 8);
            gl_lds(Bt + (size_t)(col0 + row) * KP + k0 + cg * 8, Bs + tt * 8);
        }
        __syncthreads();
        short8 a[4], b[4];
#pragma unroll
        for (int f = 0; f < 4; f++)
            a[f] = ld8(As + (wy * 64 + f * 16 + lrow) * 32 + perm);
#pragma unroll
        for (int f = 0; f < 4; f++)
            b[f] = ld8(Bs + (wx * 64 + f * 16 + lrow) * 32 + perm);
#pragma unroll
        for (int fi = 0; fi < 4; fi++)
#pragma unroll
            for (int fj = 0; fj < 4; fj++)
                acc[fi][fj] = MFMA16(a[fi], b[fj], acc[fi][fj]);
        __syncthreads();
    }
#pragma unroll
    for (int fi = 0; fi < 4; fi++)
#pragma unroll
        for (int e = 0; e < 4; e++) {
            int r = row0 + wy * 64 + fi * 16 + quad * 4 + e;
#pragma unroll
            for (int fj = 0; fj < 4; fj++) {
                int c = col0 + wx * 64 + fj * 16 + lrow;
                if (c >= 1800) continue;
                int mm = c / 450;
                int cc = c - mm * 450;
                float v = acc[fi][fj][e] + bias4[c];
                X0[(size_t)mm * XBSZ + (size_t)r * H + cc] = __float2bfloat16(v);
            }
        }
}

// p GEMM, staged+swizzled: hs @ Ub; epilogue relu(+XUa[dst]+Ptv) dot Us -> pl
__global__ __launch_bounds__(256)
void p_gemm128(const bf16* __restrict__ hs, const bf16* __restrict__ UbT,
               const bf16* __restrict__ XUa, const float* __restrict__ Ptv,
               const float* __restrict__ Us, float* __restrict__ pl) {
    __shared__ bf16 As[128 * 32];
    __shared__ bf16 Bs[128 * 32];
    int tid = threadIdx.x;
    int lane = tid & 63, wave = tid >> 6;
    int wx = wave & 1, wy = wave >> 1;
    int lrow = lane & 15, quad = lane >> 4;
    int perm = ((quad + (lrow >> 1)) & 3) * 8;
    int row0, col0;
    xcd_decode128(blockIdx.x, 4, row0, col0);
    f32x4 acc[4][4] = {};
    for (int k0i = 0; k0i < 15; k0i++) {
        int k0 = k0i * 32;
#pragma unroll
        for (int r = 0; r < 2; r++) {
            int tt = r * 256 + tid;
            int row = tt >> 2, cl = tt & 3;
            int cg = (cl - (row >> 1)) & 3;
            gl_lds(hs  + (size_t)(row0 + row) * HP + k0 + cg * 8, As + tt * 8);
            gl_lds(UbT + (size_t)(col0 + row) * KP + k0 + cg * 8, Bs + tt * 8);
        }
        __syncthreads();
        short8 a[4], b[4];
#pragma unroll
        for (int f = 0; f < 4; f++)
            a[f] = ld8(As + (wy * 64 + f * 16 + lrow) * 32 + perm);
#pragma unroll
        for (int f = 0; f < 4; f++)
            b[f] = ld8(Bs + (wx * 64 + f * 16 + lrow) * 32 + perm);
#pragma unroll
        for (int fi = 0; fi < 4; fi++)
#pragma unroll
            for (int fj = 0; fj < 4; fj++)
                acc[fi][fj] = MFMA16(a[fi], b[fj], acc[fi][fj]);
        __syncthreads();
    }
#pragma unroll
    for (int fi = 0; fi < 4; fi++)
#pragma unroll
        for (int e = 0; e < 4; e++) {
            int r = row0 + wy * 64 + fi * 16 + quad * 4 + e;
            int t = r >> 10, n = r & 1023;
            int dst = (t < 23) ? (t + 1) : (45 - t);
            float part = 0.f;
#pragma unroll
            for (int fj = 0; fj < 4; fj++) {
                int c = col0 + wx * 64 + fj * 16 + lrow;
                if (c < H) {
                    float h = fmaxf(acc[fi][fj][e] + toF(XUa[((size_t)dst * 1024 + n) * H + c])
                                    + Ptv[(size_t)n * H + c], 0.f);
                    part += h * Us[c];
                }
            }
#pragma unroll
            for (int off = 1; off < 16; off <<= 1)
                part += __shfl_xor(part, off);
            if (lrow == 0) atomicAdd(&pl[1024 + r], part);
        }
}

// Qtv/Ptv: out[n][c] = tv[n](56) @ Wlat(56x450) + bias[c]   grid(2,1024)
__global__ __launch_bounds__(256)
void tv_gemm(const float* __restrict__ tv, const float* __restrict__ Wlat,
             const float* __restrict__ bias, float* __restrict__ out) {
    int n = blockIdx.y;
    int c = blockIdx.x * 256 + threadIdx.x;
    __shared__ float tvs[LAT];
    if (threadIdx.x < LAT) tvs[threadIdx.x] = tv[n * LAT + threadIdx.x];
    __syncthreads();
    if (c < H) {
        float a = bias[c];
#pragma unroll 8
        for (int k = 0; k < LAT; k++) a += tvs[k] * Wlat[(size_t)k * H + c];
        out[(size_t)n * H + c] = a;
    }
}

// ---------------------------------------------------------------------------
// Scan K1 (MFMA, 64x64, XCD-swizzled): z_pre = S@Wzb, h_pre = RM@Whb
// ---------------------------------------------------------------------------
__global__ __launch_bounds__(256)
void scan_k1(const bf16* __restrict__ AsF, const bf16* __restrict__ AsB,
             const bf16* __restrict__ Arm,
             const bf16* __restrict__ BzT, const bf16* __restrict__ BhT,
             const bf16* __restrict__ Xz, const bf16* __restrict__ Xh,
             float* __restrict__ Sb, bf16* __restrict__ hsF, bf16* __restrict__ hsB,
             int u, int skip) {
    int tid = threadIdx.x;
    int lane = tid & 63, wave = tid >> 6;
    int wx = wave & 1, wy = wave >> 1;
    int lrow = lane & 15, quad = lane >> 4;
    int row0, col0;
    xcd_decode(blockIdx.x, 8, row0, col0);
    bool fwd = row0 < 1024;
    int rb = row0 & 1023;
    f32x4 az[2][2] = {}, ah[2][2] = {};
    if (!skip) {
        const bf16* As = (fwd ? AsF : AsB) + (size_t)(rb + wy * 32 + lrow) * HP + quad * 8;
        const bf16* Ar = Arm + (size_t)(row0 + wy * 32 + lrow) * HP + quad * 8;
        const bf16* bz0 = BzT + (size_t)(col0 + wx * 32 + lrow) * KP + quad * 8;
        const bf16* bh0 = BhT + (size_t)(col0 + wx * 32 + lrow) * KP + quad * 8;
        for (int k = 0; k < 15; k++) {
            short8 s0 = ld8(As + k * 32);
            short8 s1 = ld8(As + (size_t)16 * HP + k * 32);
            short8 r0 = ld8(Ar + k * 32);
            short8 r1 = ld8(Ar + (size_t)16 * HP + k * 32);
            short8 z0 = ld8(bz0 + k * 32);
            short8 z1 = ld8(bz0 + 16 * KP + k * 32);
            short8 h0 = ld8(bh0 + k * 32);
            short8 h1 = ld8(bh0 + 16 * KP + k * 32);
            az[0][0] = MFMA16(s0, z0, az[0][0]);
            az[0][1] = MFMA16(s0, z1, az[0][1]);
            az[1][0] = MFMA16(s1, z0, az[1][0]);
            az[1][1] = MFMA16(s1, z1, az[1][1]);
            ah[0][0] = MFMA16(r0, h0, ah[0][0]);
            ah[0][1] = MFMA16(r0, h1, ah[0][1]);
            ah[1][0] = MFMA16(r1, h0, ah[1][0]);
            ah[1][1] = MFMA16(r1, h1, ah[1][1]);
        }
    }
    int src = fwd ? u : 23 - u;
    bf16* hso = fwd ? hsF : hsB;
#pragma unroll
    for (int i = 0; i < 2; i++)
#pragma unroll
        for (int e = 0; e < 4; e++) {
            int r = row0 + wy * 32 + i * 16 + quad * 4 + e;
            int n = r & 1023;
#pragma unroll
            for (int j = 0; j < 2; j++) {
                int c = col0 + wx * 32 + j * 16 + lrow;
                if (c >= H) continue;
                float zp = az[i][j][e] + toF(Xz[((size_t)src * 1024 + n) * H + c]);
                float hp = ah[i][j][e] + toF(Xh[((size_t)src * 1024 + n) * H + c]);
                float s  = Sb[(size_t)r * H + c];
                float z  = sigm(zp);
                float mt = tanhf(hp);
                float mn = (1.f - z) * s + z * mt;
                Sb[(size_t)r * H + c] = mn;
                hso[(size_t)n * HP + c] = __float2bfloat16(mn);
            }
        }
}

// Scan K2 (MFMA): r_pre = Mnew@Ur + Xr[dst]; RMb = bf16(sig(r_pre)*Mnew)
__global__ __launch_bounds__(256)
void scan_k2(const bf16* __restrict__ AmF, const bf16* __restrict__ AmB,
             const bf16* __restrict__ UrT, const bf16* __restrict__ Xr,
             const float* __restrict__ Sb, bf16* __restrict__ RMb, int u) {
    int tid = threadIdx.x;
    int lane = tid & 63, wave = tid >> 6;
    int wx = wave & 1, wy = wave >> 1;
    int lrow = lane & 15, quad = lane >> 4;
    int row0, col0;
    xcd_decode(blockIdx.x, 8, row0, col0);
    bool fwd = row0 < 1024;
    int rb = row0 & 1023;
    const bf16* Am = (fwd ? AmF : AmB) + (size_t)(rb + wy * 32 + lrow) * HP + quad * 8;
    const bf16* b0 = UrT + (size_t)(col0 + wx * 32 + lrow) * KP + quad * 8;
    f32x4 acc[2][2] = {};
    for (int k = 0; k < 15; k++) {
        short8 a0 = ld8(Am + k * 32);
        short8 a1 = ld8(Am + (size_t)16 * HP + k * 32);
        short8 w0 = ld8(b0 + k * 32);
        short8 w1 = ld8(b0 + 16 * KP + k * 32);
        acc[0][0] = MFMA16(a0, w0, acc[0][0]);
        acc[0][1] = MFMA16(a0, w1, acc[0][1]);
        acc[1][0] = MFMA16(a1, w0, acc[1][0]);
        acc[1][1] = MFMA16(a1, w1, acc[1][1]);
    }
    int dst = fwd ? (u + 1) : (22 - u);
#pragma unroll
    for (int i = 0; i < 2; i++)
#pragma unroll
        for (int e = 0; e < 4; e++) {
            int r = row0 + wy * 32 + i * 16 + quad * 4 + e;
            int n = r & 1023;
#pragma unroll
            for (int j = 0; j < 2; j++) {
                int c = col0 + wx * 32 + j * 16 + lrow;
                if (c >= H) continue;
                float rp = acc[i][j][e] + toF(Xr[((size_t)dst * 1024 + n) * H + c]);
                float rr = sigm(rp);
                RMb[(size_t)r * HP + c] = __float2bfloat16(rr * Sb[(size_t)r * H + c]);
            }
        }
}

// hs[23+tl] += hs[21-tl] for tl in [0,22)
__global__ __launch_bounds__(256)
void hv_fixup(bf16* __restrict__ hs) {
    int idx = blockIdx.x * 256 + threadIdx.x;
    if (idx >= 22 * SLOT) return;
    int tl = idx / SLOT;
    int rem = idx - tl * SLOT;
    size_t a = (size_t)(23 + tl) * SLOT + rem;
    size_t b = (size_t)(21 - tl) * SLOT + rem;
    hs[a] = __float2bfloat16(toF(hs[a]) + toF(hs[b]));
}

// q_hidden root rows: relu(Qtv) -> qh rows 0..1023 (stride HP)
__global__ __launch_bounds__(256)
void q_root(const float* __restrict__ Qtv, bf16* __restrict__ qh) {
    int idx = blockIdx.x * 256 + threadIdx.x;
    if (idx >= 1024 * H) return;
    int n = idx / H, c = idx - n * H;
    qh[(size_t)n * HP + c] = __float2bfloat16(fmaxf(Qtv[idx], 0.f));
}

// q_reduce: wave-per-row online softmax + argmax -> per-block partials
__global__ __launch_bounds__(256)
void q_reduce(const float* __restrict__ ql, const int* __restrict__ wid,
              float* __restrict__ qred) {
    int wave = threadIdx.x >> 6, lane = threadIdx.x & 63;
    int r = blockIdx.x * 4 + wave;
    int t = r >> 10, n = r & 1023;
    int tgt = wid[n * LW + t];
    const float4* row4 = (const float4*)(ql + (size_t)r * V);
    float m = -3.4e38f, s = 0.f; int mi = 0x7fffffff;
#pragma unroll
    for (int k = 0; k < 4; k++) {
        int c4 = lane + 64 * k;
        if (c4 < 195) {
            float4 v4 = row4[c4];
            float vv[4] = {v4.x, v4.y, v4.z, v4.w};
#pragma unroll
            for (int e = 0; e < 4; e++) {
                float v = vv[e];
                if (v > m) { s = s * __expf(m - v) + 1.f; m = v; mi = c4 * 4 + e; }
                else s += __expf(v - m);
            }
        }
    }
#pragma unroll
    for (int off = 1; off < 64; off <<= 1) {
        float m2 = __shfl_xor(m, off);
        float s2 = __shfl_xor(s, off);
        int   i2 = __shfl_xor(mi, off);
        if (m2 > m || (m2 == m && i2 < mi)) {
            s = s2 + s * __expf(m - m2);
            m = m2; mi = i2;
        } else {
            s = s + s2 * __expf(m2 - m);
        }
    }
    __shared__ float lred[4][2];
    if (lane == 0) {
        float lse = m + logf(s);
        lred[wave][0] = lse - ql[(size_t)r * V + tgt];
        lred[wave][1] = (mi == tgt) ? 1.f : 0.f;
    }
    __syncthreads();
    if (threadIdx.x == 0) {
        qred[blockIdx.x * 2]     = lred[0][0] + lred[1][0] + lred[2][0] + lred[3][0];
        qred[blockIdx.x * 2 + 1] = lred[0][1] + lred[1][1] + lred[2][1] + lred[3][1];
    }
}

__global__ __launch_bounds__(256)
void q_final(const float* __restrict__ qred, float* __restrict__ out) {
    int tid = threadIdx.x;
    float L = 0.f, A = 0.f;
    for (int i = tid; i < QBLK; i += 256) { L += qred[2 * i]; A += qred[2 * i + 1]; }
    __shared__ float s1[256], s2[256];
    s1[tid] = L; s2[tid] = A;
    __syncthreads();
    for (int k = 128; k > 0; k >>= 1) {
        if (tid < k) { s1[tid] += s1[tid + k]; s2[tid] += s2[tid + k]; }
        __syncthreads();
    }
    if (tid == 0) {
        out[0] = s1[0] * (1.f / 1024.f);
        out[2] = s2[0] * (1.f / 24576.f);
    }
}

__global__ __launch_bounds__(256)
void p_init(float* __restrict__ pl, const float* __restrict__ Us_b) {
    int idx = blockIdx.x * 256 + threadIdx.x;
    if (idx < PROWS) pl[idx] = Us_b[0];
}

__global__ __launch_bounds__(256)
void p_root(const bf16* __restrict__ XUa, const float* __restrict__ Ptv,
            const float* __restrict__ Us, float* __restrict__ pl) {
    int n = blockIdx.x;
    int tid = threadIdx.x;
    const bf16* xa = XUa + (size_t)n * H;
    const float* pt = Ptv + (size_t)n * H;
    float s = 0.f;
    for (int c = tid; c < H; c += 256)
        s += fmaxf(toF(xa[c]) + pt[c], 0.f) * Us[c];
    __shared__ float red[256];
    red[tid] = s;
    __syncthreads();
    for (int k = 128; k > 0; k >>= 1) {
        if (tid < k) red[tid] += red[tid + k];
        __syncthreads();
    }
    if (tid == 0) atomicAdd(&pl[n], red[0]);
}

// BCE loss + accuracy over 48128 rows; target = (r < 23552)
__global__ __launch_bounds__(256)
void p_final(const float* __restrict__ pl, float* __restrict__ out) {
    int r = blockIdx.x * 256 + threadIdx.x;
    int tid = threadIdx.x;
    float loss = 0.f, acc = 0.f;
    if (r < PROWS) {
        float l = pl[r];
        int tgt = (r < PTGT) ? 1 : 0;
        float x = tgt ? -l : l;
        loss = fmaxf(x, 0.f) + log1pf(expf(-fabsf(x)));
        int pred = (l > 0.f) ? 1 : 0;
        acc = (pred == tgt) ? 1.f : 0.f;
    }
    __shared__ float s1[256], s2[256];
    s1[tid] = loss; s2[tid] = acc;
    __syncthreads();
    for (int k = 128; k > 0; k >>= 1) {
        if (tid < k) { s1[tid] += s1[tid + k]; s2[tid] += s2[tid + k]; }
        __syncthreads();
    }
    if (tid == 0) {
        atomicAdd(&out[1], s1[0] * (1.f / 1024.f));
        atomicAdd(&out[3], s2[0] * (1.f / 48128.f));
    }
}

// ---------------------------------------------------------------------------
extern "C" void kernel_launch(void* const* d_in, const int* in_sizes, int n_in,
                              void* d_out, int out_size, void* d_ws, size_t ws_size,
                              hipStream_t stream) {
    const int*   wid  = (const int*)  d_in[0];
    const float* tv   = (const float*)d_in[1];
    const float* emb  = (const float*)d_in[2];
    const float* W_w  = (const float*)d_in[3];
    const float* W_b  = (const float*)d_in[4];
    const float* U_w  = (const float*)d_in[5];
    const float* U_b  = (const float*)d_in[6];
    const float* Wo_w = (const float*)d_in[7];
    const float* Wo_b = (const float*)d_in[8];
    const float* Us_w = (const float*)d_in[9];
    const float* Us_b = (const float*)d_in[10];
    const float* Wz_w = (const float*)d_in[11];
    const float* Wz_b = (const float*)d_in[12];
    const float* Wr_w = (const float*)d_in[13];
    const float* Ur_w = (const float*)d_in[14];
    const float* Ur_b = (const float*)d_in[15];
    const float* Wh_w = (const float*)d_in[16];
    const float* Wh_b = (const float*)d_in[17];
    float* out = (float*)d_out;

    // ---- workspace layout (~147 MiB) ----
    char* base = (char*)d_ws;
    const size_t XBb = XBSZ * 2;                         // bytes per X block
    bf16*  Xz   = (bf16*)(base);
    bf16*  Xh   = (bf16*)(base + XBb);
    bf16*  Xr   = (bf16*)(base + 2 * XBb);
    bf16*  XUa  = (bf16*)(base + 3 * XBb);
    bf16*  hs   = (bf16*)(base + 4 * XBb);               // 46 slots x 1024 x HP
    bf16*  x_all = hs;                                   // alias (dead before scan)
    char*  p1   = base + 4 * XBb + (size_t)NE * SLOT * 2;
    bf16*  RMb  = (bf16*)p1;                p1 += (size_t)SROWS * HP * 2;
    float* Sb   = (float*)p1;               p1 += (size_t)SROWS * H * 4;
    float* Qtv  = (float*)p1;               p1 += (size_t)1024 * H * 4;
    float* Ptv  = (float*)p1;               p1 += (size_t)1024 * H * 4;
    float* pl   = (float*)p1;               p1 += (size_t)PROWS * 4;
    float* qred = (float*)p1;               p1 += (size_t)QBLK * 2 * 4;
    float* bias4 = (float*)p1;              p1 += (size_t)1856 * 4;
    bf16*  BT   = (bf16*)p1;
    // BT layout (rows of KP): BT4 1856 | Wzb 512 | Whb 512 | Ur 512 | Ub 512 |
    //                          Wtop 512 | Wo 896   (total 5312 rows ~5.1 MB)
    bf16* BT4   = BT;
    bf16* WzbT  = BT + (size_t)1856 * KP;
    bf16* WhbT  = WzbT + (size_t)512 * KP;
    bf16* UrT   = WhbT + (size_t)512 * KP;
    bf16* UbT   = UrT  + (size_t)512 * KP;
    bf16* WtopT = UbT  + (size_t)512 * KP;
    bf16* WoT   = WtopT + (size_t)512 * KP;              // 896 rows
    // q-path aliases (used after p path completes):
    bf16*  qh = (bf16*)base;                             // 24576 x HP bf16
    float* ql = (float*)(base + (size_t)QROWS * HP * 2); // 24576 x 780 f32

    // ---- init + weight prep ----
    zero_init<<<(SROWS * H + 255) / 256, 256, 0, stream>>>(out, Sb, SROWS * H);
    int btg = (512 * KP + 255) / 256;
    int btg450 = (450 * KP + 255) / 256;
    // fused pre B^T: [Wz | Wh | Wr | Ua] rows 0..1799, pad to 1856
    make_bt<<<btg450, 256, 0, stream>>>(Wz_w, H, H, H, BT4,                        450);
    make_bt<<<btg450, 256, 0, stream>>>(Wh_w, H, H, H, BT4 + (size_t)450 * KP,     450);
    make_bt<<<btg450, 256, 0, stream>>>(Wr_w, H, H, H, BT4 + (size_t)900 * KP,     450);
    make_bt<<<(506 * KP + 255) / 256, 256, 0, stream>>>(U_w, H, H, H, BT4 + (size_t)1350 * KP, 506);
    pack_bias<<<8, 256, 0, stream>>>(Wz_b, Wh_b, Ur_b, bias4);
    make_bt<<<btg, 256, 0, stream>>>(Wz_w + 450*450,  H, H, H, WzbT, 512);
    make_bt<<<btg, 256, 0, stream>>>(Wh_w + 450*450,  H, H, H, WhbT, 512);
    make_bt<<<btg, 256, 0, stream>>>(Ur_w,            H, H, H, UrT,  512);
    make_bt<<<btg, 256, 0, stream>>>(U_w + 450*450,   H, H, H, UbT,  512);
    make_bt<<<btg, 256, 0, stream>>>(W_w,             H, H, H, WtopT, 512);
    make_bt<<<(896 * KP + 255) / 256, 256, 0, stream>>>(Wo_w, H, V, V, WoT, 896);

    // ---- embedding gather + fused per-node precompute (one GEMM, N=1800) ----
    gather_x<<<(24 * 1024 * 225 + 255) / 256, 256, 0, stream>>>(emb, wid, x_all);
    gemm128_pre<<<(QROWS / 128) * 15, 256, 0, stream>>>(x_all, BT4, Xz, bias4);

    tv_gemm<<<dim3(2, 1024), 256, 0, stream>>>(tv, W_w + 450*450, W_b, Qtv);
    tv_gemm<<<dim3(2, 1024), 256, 0, stream>>>(tv, U_w + 900*450, U_b, Ptv);

    // ---- sequential scan: 23 steps, fwd+bwd chains batched (M=2048) ----
    for (int u = 0; u < 23; u++) {
        const bf16* AsF = hs + (size_t)(u - 1) * SLOT;        // valid only u>0
        const bf16* AsB = hs + (size_t)(22 + u) * SLOT;
        scan_k1<<<256, 256, 0, stream>>>(AsF, AsB, RMb, WzbT, WhbT, Xz, Xh,
                                         Sb, hs + (size_t)u * SLOT,
                                         hs + (size_t)(23 + u) * SLOT, u, u == 0 ? 1 : 0);
        if (u < 22)
            scan_k2<<<256, 256, 0, stream>>>(hs + (size_t)u * SLOT, hs + (size_t)(23 + u) * SLOT,
                                             UrT, Xr, Sb, RMb, u);
    }
    hv_fixup<<<(22 * SLOT + 255) / 256, 256, 0, stream>>>(hs);

    // ---- p path (before q aliases X blocks / hs) ----
    p_init<<<(PROWS + 255) / 256, 256, 0, stream>>>(pl, Us_b);
    p_root<<<1024, 256, 0, stream>>>(XUa, Ptv, Us_w, pl);
    p_gemm128<<<(PROWS - 1024) / 128 * 4, 256, 0, stream>>>(hs, UbT, XUa, Ptv, Us_w, pl);
    p_final<<<PROWS / 256, 256, 0, stream>>>(pl, out);

    // ---- q path (qh over Xz/Xh; ql over Xr/XUa/hs-head) ----
    q_root<<<(1024 * H + 255) / 256, 256, 0, stream>>>(Qtv, qh);
    gemm128<bf16><<<(NF * 1024 / 128) * 4, 256, 0, stream>>>(hs, HP, WtopT, H, 4,
                                                             qh + (size_t)1024 * HP, HP,
                                                             (const float*)nullptr, Qtv, H, 1);
    gemm128<float><<<(QROWS / 128) * 7, 256, 0, stream>>>(qh, HP, WoT, V, 7, ql, V,
                                                          Wo_b, (const float*)nullptr, H, 0);
    q_reduce<<<QBLK, 256, 0, stream>>>(ql, wid, qred);
    q_final<<<1, 256, 0, stream>>>(qred, out);

    (void)in_sizes; (void)n_in; (void)out_size; (void)ws_size;
}

// Round 11
// 1090.789 us; speedup vs baseline: 3.0491x; 1.0118x over previous
//
#include <hip/hip_runtime.h>
#include <hip/hip_bf16.h>
#include <math.h>

#define H 450
#define HP 464            // padded A row stride (bf16 elems; 16B-aligned rows)
#define KP 480            // padded K extent: 15 MFMA chunks of 32
#define LAT 56
#define V 780
#define LW 24
#define NE 46
#define NF 23
#define SLOT (1024*HP)
#define SROWS 2048
#define QROWS (24*1024)
#define PROWS (47*1024)
#define PTGT  (23*1024)
#define QBLK 6144
#define XBSZ ((size_t)QROWS * H)      // one X block, elems

typedef __hip_bfloat16 bf16;
typedef __attribute__((ext_vector_type(8))) short short8;
typedef __attribute__((ext_vector_type(4))) float f32x4;

#define MFMA16(a,b,c) __builtin_amdgcn_mfma_f32_16x16x32_bf16(a,b,c,0,0,0)

__device__ __forceinline__ float sigm(float x) { return 1.f / (1.f + expf(-x)); }
__device__ __forceinline__ float toF(bf16 x) { return __bfloat162float(x); }
__device__ __forceinline__ void stV(float* p, float v) { *p = v; }
__device__ __forceinline__ void stV(bf16* p, float v) { *p = __float2bfloat16(v); }
__device__ __forceinline__ short8 ld8(const bf16* p) { return *reinterpret_cast<const short8*>(p); }

// async global->LDS, 16B/lane; LDS dest is wave-uniform base + lane*16
__device__ __forceinline__ void gl_lds(const bf16* g, bf16* l) {
    __builtin_amdgcn_global_load_lds(
        (const __attribute__((address_space(1))) void*)g,
        (__attribute__((address_space(3))) void*)l, 16, 0, 0);
}

// 128-tile XCD swizzle
__device__ __forceinline__ void xcd_decode128(int b, int C, int& row0, int& col0) {
    int rres = b & 7;
    int colt = (b >> 3) % C;
    int g    = b / (8 * C);
    row0 = (rres + 8 * g) * 128;
    col0 = colt * 128;
}
// scan 32-row tiles: grid 512 = 64 row-tiles x 8 col-tiles
__device__ __forceinline__ void xcd_decode32(int b, int& row0, int& col0) {
    int rres = b & 7;
    int colt = (b >> 3) & 7;
    int g    = b >> 6;                // 0..7
    row0 = (rres + 8 * g) * 32;
    col0 = colt * 64;
}

// ---------------------------------------------------------------------------
__global__ __launch_bounds__(256)
void make_bt(const float* __restrict__ src, int K, int N, int ld,
             bf16* __restrict__ dst, int npad) {
    int idx = blockIdx.x * 256 + threadIdx.x;
    if (idx >= npad * KP) return;
    int n = idx / KP, k = idx - n * KP;
    float v = (n < N && k < K) ? src[(size_t)k * ld + n] : 0.f;
    dst[idx] = __float2bfloat16(v);
}

// combined bias for fused pre-GEMM: [Wz_b | Wh_b | Ur_b | 0]
__global__ __launch_bounds__(256)
void pack_bias(const float* __restrict__ zb, const float* __restrict__ hb,
               const float* __restrict__ rb, float* __restrict__ bias4) {
    int i = blockIdx.x * 256 + threadIdx.x;
    if (i >= 1856) return;
    float v = 0.f;
    if (i < 450)       v = zb[i];
    else if (i < 900)  v = hb[i - 450];
    else if (i < 1350) v = rb[i - 900];
    bias4[i] = v;
}

__global__ __launch_bounds__(256)
void zero_init(float* __restrict__ out, float* __restrict__ Sb, int n) {
    int i = blockIdx.x * 256 + threadIdx.x;
    if (i < 4) out[i] = 0.f;
    if (i < n) Sb[i] = 0.f;
}

// x_all[t*1024+n][h] = emb[wid[n][t]][h]  (bf16, stride HP)
__global__ __launch_bounds__(256)
void gather_x(const float* __restrict__ emb, const int* __restrict__ wid,
              bf16* __restrict__ x_all) {
    int e = blockIdx.x * 256 + threadIdx.x;
    if (e >= 24 * 1024 * 225) return;
    int row = e / 225, h2 = e - row * 225;
    int t = row >> 10, n = row & 1023;
    int v = wid[n * LW + t];
    float2 x = ((const float2*)(emb + (size_t)v * H))[h2];
    bf16* dst = x_all + (size_t)row * HP + 2 * h2;
    dst[0] = __float2bfloat16(x.x);
    dst[1] = __float2bfloat16(x.y);
}

// ---------------------------------------------------------------------------
// LDS-staged GEMM: 128x128 tile, BK=32, global_load_lds + rotate swizzle
// ---------------------------------------------------------------------------
template<typename TC>
__global__ __launch_bounds__(256)
void gemm128(const bf16* __restrict__ A, int lda,
             const bf16* __restrict__ Bt, int N, int cblk,
             TC* __restrict__ C, int ldc,
             const float* __restrict__ bias,
             const float* __restrict__ addrow, int addld, int relu) {
    __shared__ bf16 As[128 * 32];
    __shared__ bf16 Bs[128 * 32];
    int tid = threadIdx.x;
    int lane = tid & 63, wave = tid >> 6;
    int wx = wave & 1, wy = wave >> 1;
    int lrow = lane & 15, quad = lane >> 4;
    int perm = ((quad + (lrow >> 1)) & 3) * 8;
    int row0, col0;
    xcd_decode128(blockIdx.x, cblk, row0, col0);
    f32x4 acc[4][4] = {};
    for (int k0i = 0; k0i < 15; k0i++) {
        int k0 = k0i * 32;
#pragma unroll
        for (int r = 0; r < 2; r++) {
            int tt = r * 256 + tid;
            int row = tt >> 2, cl = tt & 3;
            int cg = (cl - (row >> 1)) & 3;
            gl_lds(A  + (size_t)(row0 + row) * lda + k0 + cg * 8, As + tt * 8);
            gl_lds(Bt + (size_t)(col0 + row) * KP  + k0 + cg * 8, Bs + tt * 8);
        }
        __syncthreads();
        short8 a[4], b[4];
#pragma unroll
        for (int f = 0; f < 4; f++)
            a[f] = ld8(As + (wy * 64 + f * 16 + lrow) * 32 + perm);
#pragma unroll
        for (int f = 0; f < 4; f++)
            b[f] = ld8(Bs + (wx * 64 + f * 16 + lrow) * 32 + perm);
#pragma unroll
        for (int fi = 0; fi < 4; fi++)
#pragma unroll
            for (int fj = 0; fj < 4; fj++)
                acc[fi][fj] = MFMA16(a[fi], b[fj], acc[fi][fj]);
        __syncthreads();
    }
#pragma unroll
    for (int fi = 0; fi < 4; fi++)
#pragma unroll
        for (int e = 0; e < 4; e++) {
            int r = row0 + wy * 64 + fi * 16 + quad * 4 + e;
#pragma unroll
            for (int fj = 0; fj < 4; fj++) {
                int c = col0 + wx * 64 + fj * 16 + lrow;
                if (c >= N) continue;
                float v = acc[fi][fj][e];
                if (bias) v += bias[c];
                if (addrow) v += addrow[(size_t)(r & 1023) * addld + c];
                if (relu) v = fmaxf(v, 0.f);
                stV(&C[(size_t)r * ldc + c], v);
            }
        }
}

// Fused pre-GEMM: X @ [Wz|Wh|Wr|Ua] (N=1800), demux epilogue into 4 X blocks
__global__ __launch_bounds__(256)
void gemm128_pre(const bf16* __restrict__ A,
                 const bf16* __restrict__ Bt,
                 bf16* __restrict__ X0,          // Xz; blocks stride XBSZ
                 const float* __restrict__ bias4) {
    __shared__ bf16 As[128 * 32];
    __shared__ bf16 Bs[128 * 32];
    int tid = threadIdx.x;
    int lane = tid & 63, wave = tid >> 6;
    int wx = wave & 1, wy = wave >> 1;
    int lrow = lane & 15, quad = lane >> 4;
    int perm = ((quad + (lrow >> 1)) & 3) * 8;
    int row0, col0;
    xcd_decode128(blockIdx.x, 15, row0, col0);
    f32x4 acc[4][4] = {};
    for (int k0i = 0; k0i < 15; k0i++) {
        int k0 = k0i * 32;
#pragma unroll
        for (int r = 0; r < 2; r++) {
            int tt = r * 256 + tid;
            int row = tt >> 2, cl = tt & 3;
            int cg = (cl - (row >> 1)) & 3;
            gl_lds(A  + (size_t)(row0 + row) * HP + k0 + cg * 8, As + tt * 8);
            gl_lds(Bt + (size_t)(col0 + row) * KP + k0 + cg * 8, Bs + tt * 8);
        }
        __syncthreads();
        short8 a[4], b[4];
#pragma unroll
        for (int f = 0; f < 4; f++)
            a[f] = ld8(As + (wy * 64 + f * 16 + lrow) * 32 + perm);
#pragma unroll
        for (int f = 0; f < 4; f++)
            b[f] = ld8(Bs + (wx * 64 + f * 16 + lrow) * 32 + perm);
#pragma unroll
        for (int fi = 0; fi < 4; fi++)
#pragma unroll
            for (int fj = 0; fj < 4; fj++)
                acc[fi][fj] = MFMA16(a[fi], b[fj], acc[fi][fj]);
        __syncthreads();
    }
#pragma unroll
    for (int fi = 0; fi < 4; fi++)
#pragma unroll
        for (int e = 0; e < 4; e++) {
            int r = row0 + wy * 64 + fi * 16 + quad * 4 + e;
#pragma unroll
            for (int fj = 0; fj < 4; fj++) {
                int c = col0 + wx * 64 + fj * 16 + lrow;
                if (c >= 1800) continue;
                int mm = c / 450;
                int cc = c - mm * 450;
                float v = acc[fi][fj][e] + bias4[c];
                X0[(size_t)mm * XBSZ + (size_t)r * H + cc] = __float2bfloat16(v);
            }
        }
}

// p GEMM, staged+swizzled: hs @ Ub; epilogue relu(+XUa[dst]+Ptv) dot Us -> pl
__global__ __launch_bounds__(256)
void p_gemm128(const bf16* __restrict__ hs, const bf16* __restrict__ UbT,
               const bf16* __restrict__ XUa, const float* __restrict__ Ptv,
               const float* __restrict__ Us, float* __restrict__ pl) {
    __shared__ bf16 As[128 * 32];
    __shared__ bf16 Bs[128 * 32];
    int tid = threadIdx.x;
    int lane = tid & 63, wave = tid >> 6;
    int wx = wave & 1, wy = wave >> 1;
    int lrow = lane & 15, quad = lane >> 4;
    int perm = ((quad + (lrow >> 1)) & 3) * 8;
    int row0, col0;
    xcd_decode128(blockIdx.x, 4, row0, col0);
    f32x4 acc[4][4] = {};
    for (int k0i = 0; k0i < 15; k0i++) {
        int k0 = k0i * 32;
#pragma unroll
        for (int r = 0; r < 2; r++) {
            int tt = r * 256 + tid;
            int row = tt >> 2, cl = tt & 3;
            int cg = (cl - (row >> 1)) & 3;
            gl_lds(hs  + (size_t)(row0 + row) * HP + k0 + cg * 8, As + tt * 8);
            gl_lds(UbT + (size_t)(col0 + row) * KP + k0 + cg * 8, Bs + tt * 8);
        }
        __syncthreads();
        short8 a[4], b[4];
#pragma unroll
        for (int f = 0; f < 4; f++)
            a[f] = ld8(As + (wy * 64 + f * 16 + lrow) * 32 + perm);
#pragma unroll
        for (int f = 0; f < 4; f++)
            b[f] = ld8(Bs + (wx * 64 + f * 16 + lrow) * 32 + perm);
#pragma unroll
        for (int fi = 0; fi < 4; fi++)
#pragma unroll
            for (int fj = 0; fj < 4; fj++)
                acc[fi][fj] = MFMA16(a[fi], b[fj], acc[fi][fj]);
        __syncthreads();
    }
#pragma unroll
    for (int fi = 0; fi < 4; fi++)
#pragma unroll
        for (int e = 0; e < 4; e++) {
            int r = row0 + wy * 64 + fi * 16 + quad * 4 + e;
            int t = r >> 10, n = r & 1023;
            int dst = (t < 23) ? (t + 1) : (45 - t);
            float part = 0.f;
#pragma unroll
            for (int fj = 0; fj < 4; fj++) {
                int c = col0 + wx * 64 + fj * 16 + lrow;
                if (c < H) {
                    float h = fmaxf(acc[fi][fj][e] + toF(XUa[((size_t)dst * 1024 + n) * H + c])
                                    + Ptv[(size_t)n * H + c], 0.f);
                    part += h * Us[c];
                }
            }
#pragma unroll
            for (int off = 1; off < 16; off <<= 1)
                part += __shfl_xor(part, off);
            if (lrow == 0) atomicAdd(&pl[1024 + r], part);
        }
}

// Qtv/Ptv: out[n][c] = tv[n](56) @ Wlat(56x450) + bias[c]   grid(2,1024)
__global__ __launch_bounds__(256)
void tv_gemm(const float* __restrict__ tv, const float* __restrict__ Wlat,
             const float* __restrict__ bias, float* __restrict__ out) {
    int n = blockIdx.y;
    int c = blockIdx.x * 256 + threadIdx.x;
    __shared__ float tvs[LAT];
    if (threadIdx.x < LAT) tvs[threadIdx.x] = tv[n * LAT + threadIdx.x];
    __syncthreads();
    if (c < H) {
        float a = bias[c];
#pragma unroll 8
        for (int k = 0; k < LAT; k++) a += tvs[k] * Wlat[(size_t)k * H + c];
        out[(size_t)n * H + c] = a;
    }
}

// ---------------------------------------------------------------------------
// Scan K1 (MFMA, 32x64 tiles, 512 blocks = 2/CU, 8 waves/CU):
// z_pre = S@Wzb, h_pre = RM@Whb  (M=2048,N=450,K=450)
// ---------------------------------------------------------------------------
__global__ __launch_bounds__(256)
void scan_k1(const bf16* __restrict__ AsF, const bf16* __restrict__ AsB,
             const bf16* __restrict__ Arm,
             const bf16* __restrict__ BzT, const bf16* __restrict__ BhT,
             const bf16* __restrict__ Xz, const bf16* __restrict__ Xh,
             float* __restrict__ Sb, bf16* __restrict__ hsF, bf16* __restrict__ hsB,
             int u, int skip) {
    int tid = threadIdx.x;
    int lane = tid & 63, wave = tid >> 6;
    int wx = wave & 1, wy = wave >> 1;           // wave: 16 rows x 32 cols
    int lrow = lane & 15, quad = lane >> 4;
    int row0, col0;
    xcd_decode32(blockIdx.x, row0, col0);
    bool fwd = row0 < 1024;
    int rb = row0 & 1023;
    f32x4 az[2] = {}, ah[2] = {};
    if (!skip) {
        const bf16* As = (fwd ? AsF : AsB) + (size_t)(rb + wy * 16 + lrow) * HP + quad * 8;
        const bf16* Ar = Arm + (size_t)(row0 + wy * 16 + lrow) * HP + quad * 8;
        const bf16* bz0 = BzT + (size_t)(col0 + wx * 32 + lrow) * KP + quad * 8;
        const bf16* bh0 = BhT + (size_t)(col0 + wx * 32 + lrow) * KP + quad * 8;
        for (int k = 0; k < 15; k++) {
            short8 s0 = ld8(As + k * 32);
            short8 r0 = ld8(Ar + k * 32);
            short8 z0 = ld8(bz0 + k * 32);
            short8 z1 = ld8(bz0 + 16 * KP + k * 32);
            short8 h0 = ld8(bh0 + k * 32);
            short8 h1 = ld8(bh0 + 16 * KP + k * 32);
            az[0] = MFMA16(s0, z0, az[0]);
            az[1] = MFMA16(s0, z1, az[1]);
            ah[0] = MFMA16(r0, h0, ah[0]);
            ah[1] = MFMA16(r0, h1, ah[1]);
        }
    }
    int src = fwd ? u : 23 - u;
    bf16* hso = fwd ? hsF : hsB;
#pragma unroll
    for (int e = 0; e < 4; e++) {
        int r = row0 + wy * 16 + quad * 4 + e;
        int n = r & 1023;
#pragma unroll
        for (int j = 0; j < 2; j++) {
            int c = col0 + wx * 32 + j * 16 + lrow;
            if (c >= H) continue;
            float zp = az[j][e] + toF(Xz[((size_t)src * 1024 + n) * H + c]);
            float hp = ah[j][e] + toF(Xh[((size_t)src * 1024 + n) * H + c]);
            float s  = Sb[(size_t)r * H + c];
            float z  = sigm(zp);
            float mt = tanhf(hp);
            float mn = (1.f - z) * s + z * mt;
            Sb[(size_t)r * H + c] = mn;
            hso[(size_t)n * HP + c] = __float2bfloat16(mn);
        }
    }
}

// Scan K2 (MFMA, 32x64): r_pre = Mnew@Ur + Xr[dst]; RMb = sig(r_pre)*Mnew
__global__ __launch_bounds__(256)
void scan_k2(const bf16* __restrict__ AmF, const bf16* __restrict__ AmB,
             const bf16* __restrict__ UrT, const bf16* __restrict__ Xr,
             const float* __restrict__ Sb, bf16* __restrict__ RMb, int u) {
    int tid = threadIdx.x;
    int lane = tid & 63, wave = tid >> 6;
    int wx = wave & 1, wy = wave >> 1;
    int lrow = lane & 15, quad = lane >> 4;
    int row0, col0;
    xcd_decode32(blockIdx.x, row0, col0);
    bool fwd = row0 < 1024;
    int rb = row0 & 1023;
    const bf16* Am = (fwd ? AmF : AmB) + (size_t)(rb + wy * 16 + lrow) * HP + quad * 8;
    const bf16* b0 = UrT + (size_t)(col0 + wx * 32 + lrow) * KP + quad * 8;
    f32x4 acc[2] = {};
    for (int k = 0; k < 15; k++) {
        short8 a0 = ld8(Am + k * 32);
        short8 w0 = ld8(b0 + k * 32);
        short8 w1 = ld8(b0 + 16 * KP + k * 32);
        acc[0] = MFMA16(a0, w0, acc[0]);
        acc[1] = MFMA16(a0, w1, acc[1]);
    }
    int dst = fwd ? (u + 1) : (22 - u);
#pragma unroll
    for (int e = 0; e < 4; e++) {
        int r = row0 + wy * 16 + quad * 4 + e;
        int n = r & 1023;
#pragma unroll
        for (int j = 0; j < 2; j++) {
            int c = col0 + wx * 32 + j * 16 + lrow;
            if (c >= H) continue;
            float rp = acc[j][e] + toF(Xr[((size_t)dst * 1024 + n) * H + c]);
            float rr = sigm(rp);
            RMb[(size_t)r * HP + c] = __float2bfloat16(rr * Sb[(size_t)r * H + c]);
        }
    }
}

// hs[23+tl] += hs[21-tl] for tl in [0,22)
__global__ __launch_bounds__(256)
void hv_fixup(bf16* __restrict__ hs) {
    int idx = blockIdx.x * 256 + threadIdx.x;
    if (idx >= 22 * SLOT) return;
    int tl = idx / SLOT;
    int rem = idx - tl * SLOT;
    size_t a = (size_t)(23 + tl) * SLOT + rem;
    size_t b = (size_t)(21 - tl) * SLOT + rem;
    hs[a] = __float2bfloat16(toF(hs[a]) + toF(hs[b]));
}

// q_hidden root rows: relu(Qtv) -> qh rows 0..1023 (stride HP)
__global__ __launch_bounds__(256)
void q_root(const float* __restrict__ Qtv, bf16* __restrict__ qh) {
    int idx = blockIdx.x * 256 + threadIdx.x;
    if (idx >= 1024 * H) return;
    int n = idx / H, c = idx - n * H;
    qh[(size_t)n * HP + c] = __float2bfloat16(fmaxf(Qtv[idx], 0.f));
}

// q_reduce: wave-per-row online softmax + argmax -> per-block partials
__global__ __launch_bounds__(256)
void q_reduce(const float* __restrict__ ql, const int* __restrict__ wid,
              float* __restrict__ qred) {
    int wave = threadIdx.x >> 6, lane = threadIdx.x & 63;
    int r = blockIdx.x * 4 + wave;
    int t = r >> 10, n = r & 1023;
    int tgt = wid[n * LW + t];
    const float4* row4 = (const float4*)(ql + (size_t)r * V);
    float m = -3.4e38f, s = 0.f; int mi = 0x7fffffff;
#pragma unroll
    for (int k = 0; k < 4; k++) {
        int c4 = lane + 64 * k;
        if (c4 < 195) {
            float4 v4 = row4[c4];
            float vv[4] = {v4.x, v4.y, v4.z, v4.w};
#pragma unroll
            for (int e = 0; e < 4; e++) {
                float v = vv[e];
                if (v > m) { s = s * __expf(m - v) + 1.f; m = v; mi = c4 * 4 + e; }
                else s += __expf(v - m);
            }
        }
    }
#pragma unroll
    for (int off = 1; off < 64; off <<= 1) {
        float m2 = __shfl_xor(m, off);
        float s2 = __shfl_xor(s, off);
        int   i2 = __shfl_xor(mi, off);
        if (m2 > m || (m2 == m && i2 < mi)) {
            s = s2 + s * __expf(m - m2);
            m = m2; mi = i2;
        } else {
            s = s + s2 * __expf(m2 - m);
        }
    }
    __shared__ float lred[4][2];
    if (lane == 0) {
        float lse = m + logf(s);
        lred[wave][0] = lse - ql[(size_t)r * V + tgt];
        lred[wave][1] = (mi == tgt) ? 1.f : 0.f;
    }
    __syncthreads();
    if (threadIdx.x == 0) {
        qred[blockIdx.x * 2]     = lred[0][0] + lred[1][0] + lred[2][0] + lred[3][0];
        qred[blockIdx.x * 2 + 1] = lred[0][1] + lred[1][1] + lred[2][1] + lred[3][1];
    }
}

__global__ __launch_bounds__(256)
void q_final(const float* __restrict__ qred, float* __restrict__ out) {
    int tid = threadIdx.x;
    float L = 0.f, A = 0.f;
    for (int i = tid; i < QBLK; i += 256) { L += qred[2 * i]; A += qred[2 * i + 1]; }
    __shared__ float s1[256], s2[256];
    s1[tid] = L; s2[tid] = A;
    __syncthreads();
    for (int k = 128; k > 0; k >>= 1) {
        if (tid < k) { s1[tid] += s1[tid + k]; s2[tid] += s2[tid + k]; }
        __syncthreads();
    }
    if (tid == 0) {
        out[0] = s1[0] * (1.f / 1024.f);
        out[2] = s2[0] * (1.f / 24576.f);
    }
}

__global__ __launch_bounds__(256)
void p_init(float* __restrict__ pl, const float* __restrict__ Us_b) {
    int idx = blockIdx.x * 256 + threadIdx.x;
    if (idx < PROWS) pl[idx] = Us_b[0];
}

__global__ __launch_bounds__(256)
void p_root(const bf16* __restrict__ XUa, const float* __restrict__ Ptv,
            const float* __restrict__ Us, float* __restrict__ pl) {
    int n = blockIdx.x;
    int tid = threadIdx.x;
    const bf16* xa = XUa + (size_t)n * H;
    const float* pt = Ptv + (size_t)n * H;
    float s = 0.f;
    for (int c = tid; c < H; c += 256)
        s += fmaxf(toF(xa[c]) + pt[c], 0.f) * Us[c];
    __shared__ float red[256];
    red[tid] = s;
    __syncthreads();
    for (int k = 128; k > 0; k >>= 1) {
        if (tid < k) red[tid] += red[tid + k];
        __syncthreads();
    }
    if (tid == 0) atomicAdd(&pl[n], red[0]);
}

// BCE loss + accuracy over 48128 rows; target = (r < 23552)
__global__ __launch_bounds__(256)
void p_final(const float* __restrict__ pl, float* __restrict__ out) {
    int r = blockIdx.x * 256 + threadIdx.x;
    int tid = threadIdx.x;
    float loss = 0.f, acc = 0.f;
    if (r < PROWS) {
        float l = pl[r];
        int tgt = (r < PTGT) ? 1 : 0;
        float x = tgt ? -l : l;
        loss = fmaxf(x, 0.f) + log1pf(expf(-fabsf(x)));
        int pred = (l > 0.f) ? 1 : 0;
        acc = (pred == tgt) ? 1.f : 0.f;
    }
    __shared__ float s1[256], s2[256];
    s1[tid] = loss; s2[tid] = acc;
    __syncthreads();
    for (int k = 128; k > 0; k >>= 1) {
        if (tid < k) { s1[tid] += s1[tid + k]; s2[tid] += s2[tid + k]; }
        __syncthreads();
    }
    if (tid == 0) {
        atomicAdd(&out[1], s1[0] * (1.f / 1024.f));
        atomicAdd(&out[3], s2[0] * (1.f / 48128.f));
    }
}

// ---------------------------------------------------------------------------
extern "C" void kernel_launch(void* const* d_in, const int* in_sizes, int n_in,
                              void* d_out, int out_size, void* d_ws, size_t ws_size,
                              hipStream_t stream) {
    const int*   wid  = (const int*)  d_in[0];
    const float* tv   = (const float*)d_in[1];
    const float* emb  = (const float*)d_in[2];
    const float* W_w  = (const float*)d_in[3];
    const float* W_b  = (const float*)d_in[4];
    const float* U_w  = (const float*)d_in[5];
    const float* U_b  = (const float*)d_in[6];
    const float* Wo_w = (const float*)d_in[7];
    const float* Wo_b = (const float*)d_in[8];
    const float* Us_w = (const float*)d_in[9];
    const float* Us_b = (const float*)d_in[10];
    const float* Wz_w = (const float*)d_in[11];
    const float* Wz_b = (const float*)d_in[12];
    const float* Wr_w = (const float*)d_in[13];
    const float* Ur_w = (const float*)d_in[14];
    const float* Ur_b = (const float*)d_in[15];
    const float* Wh_w = (const float*)d_in[16];
    const float* Wh_b = (const float*)d_in[17];
    float* out = (float*)d_out;

    // ---- workspace layout (~147 MiB) ----
    char* base = (char*)d_ws;
    const size_t XBb = XBSZ * 2;                         // bytes per X block
    bf16*  Xz   = (bf16*)(base);
    bf16*  Xh   = (bf16*)(base + XBb);
    bf16*  Xr   = (bf16*)(base + 2 * XBb);
    bf16*  XUa  = (bf16*)(base + 3 * XBb);
    bf16*  hs   = (bf16*)(base + 4 * XBb);               // 46 slots x 1024 x HP
    bf16*  x_all = hs;                                   // alias (dead before scan)
    char*  p1   = base + 4 * XBb + (size_t)NE * SLOT * 2;
    bf16*  RMb  = (bf16*)p1;                p1 += (size_t)SROWS * HP * 2;
    float* Sb   = (float*)p1;               p1 += (size_t)SROWS * H * 4;
    float* Qtv  = (float*)p1;               p1 += (size_t)1024 * H * 4;
    float* Ptv  = (float*)p1;               p1 += (size_t)1024 * H * 4;
    float* pl   = (float*)p1;               p1 += (size_t)PROWS * 4;
    float* qred = (float*)p1;               p1 += (size_t)QBLK * 2 * 4;
    float* bias4 = (float*)p1;              p1 += (size_t)1856 * 4;
    bf16*  BT   = (bf16*)p1;
    bf16* BT4   = BT;
    bf16* WzbT  = BT + (size_t)1856 * KP;
    bf16* WhbT  = WzbT + (size_t)512 * KP;
    bf16* UrT   = WhbT + (size_t)512 * KP;
    bf16* UbT   = UrT  + (size_t)512 * KP;
    bf16* WtopT = UbT  + (size_t)512 * KP;
    bf16* WoT   = WtopT + (size_t)512 * KP;              // 896 rows
    // q-path aliases (used after p path completes):
    bf16*  qh = (bf16*)base;                             // 24576 x HP bf16
    float* ql = (float*)(base + (size_t)QROWS * HP * 2); // 24576 x 780 f32

    // ---- init + weight prep ----
    zero_init<<<(SROWS * H + 255) / 256, 256, 0, stream>>>(out, Sb, SROWS * H);
    int btg = (512 * KP + 255) / 256;
    int btg450 = (450 * KP + 255) / 256;
    make_bt<<<btg450, 256, 0, stream>>>(Wz_w, H, H, H, BT4,                        450);
    make_bt<<<btg450, 256, 0, stream>>>(Wh_w, H, H, H, BT4 + (size_t)450 * KP,     450);
    make_bt<<<btg450, 256, 0, stream>>>(Wr_w, H, H, H, BT4 + (size_t)900 * KP,     450);
    make_bt<<<(506 * KP + 255) / 256, 256, 0, stream>>>(U_w, H, H, H, BT4 + (size_t)1350 * KP, 506);
    pack_bias<<<8, 256, 0, stream>>>(Wz_b, Wh_b, Ur_b, bias4);
    make_bt<<<btg, 256, 0, stream>>>(Wz_w + 450*450,  H, H, H, WzbT, 512);
    make_bt<<<btg, 256, 0, stream>>>(Wh_w + 450*450,  H, H, H, WhbT, 512);
    make_bt<<<btg, 256, 0, stream>>>(Ur_w,            H, H, H, UrT,  512);
    make_bt<<<btg, 256, 0, stream>>>(U_w + 450*450,   H, H, H, UbT,  512);
    make_bt<<<btg, 256, 0, stream>>>(W_w,             H, H, H, WtopT, 512);
    make_bt<<<(896 * KP + 255) / 256, 256, 0, stream>>>(Wo_w, H, V, V, WoT, 896);

    // ---- embedding gather + fused per-node precompute (one GEMM, N=1800) ----
    gather_x<<<(24 * 1024 * 225 + 255) / 256, 256, 0, stream>>>(emb, wid, x_all);
    gemm128_pre<<<(QROWS / 128) * 15, 256, 0, stream>>>(x_all, BT4, Xz, bias4);

    tv_gemm<<<dim3(2, 1024), 256, 0, stream>>>(tv, W_w + 450*450, W_b, Qtv);
    tv_gemm<<<dim3(2, 1024), 256, 0, stream>>>(tv, U_w + 900*450, U_b, Ptv);

    // ---- sequential scan: 23 steps, 32x64 tiles, 512 blocks (2/CU) ----
    for (int u = 0; u < 23; u++) {
        const bf16* AsF = hs + (size_t)(u - 1) * SLOT;        // valid only u>0
        const bf16* AsB = hs + (size_t)(22 + u) * SLOT;
        scan_k1<<<512, 256, 0, stream>>>(AsF, AsB, RMb, WzbT, WhbT, Xz, Xh,
                                         Sb, hs + (size_t)u * SLOT,
                                         hs + (size_t)(23 + u) * SLOT, u, u == 0 ? 1 : 0);
        if (u < 22)
            scan_k2<<<512, 256, 0, stream>>>(hs + (size_t)u * SLOT, hs + (size_t)(23 + u) * SLOT,
                                             UrT, Xr, Sb, RMb, u);
    }
    hv_fixup<<<(22 * SLOT + 255) / 256, 256, 0, stream>>>(hs);

    // ---- p path (before q aliases X blocks / hs) ----
    p_init<<<(PROWS + 255) / 256, 256, 0, stream>>>(pl, Us_b);
    p_root<<<1024, 256, 0, stream>>>(XUa, Ptv, Us_w, pl);
    p_gemm128<<<(PROWS - 1024) / 128 * 4, 256, 0, stream>>>(hs, UbT, XUa, Ptv, Us_w, pl);
    p_final<<<PROWS / 256, 256, 0, stream>>>(pl, out);

    // ---- q path (qh over Xz/Xh; ql over Xr/XUa/hs-head) ----
    q_root<<<(1024 * H + 255) / 256, 256, 0, stream>>>(Qtv, qh);
    gemm128<bf16><<<(NF * 1024 / 128) * 4, 256, 0, stream>>>(hs, HP, WtopT, H, 4,
                                                             qh + (size_t)1024 * HP, HP,
                                                             (const float*)nullptr, Qtv, H, 1);
    gemm128<float><<<(QROWS / 128) * 7, 256, 0, stream>>>(qh, HP, WoT, V, 7, ql, V,
                                                          Wo_b, (const float*)nullptr, H, 0);
    q_reduce<<<QBLK, 256, 0, stream>>>(ql, wid, qred);
    q_final<<<1, 256, 0, stream>>>(qred, out);

    (void)in_sizes; (void)n_in; (void)out_size; (void)ws_size;
}